// Round 8
// baseline (265.470 us; speedup 1.0000x reference)
//
#include <hip/hip_runtime.h>
#include <math.h>

#define B_    2
#define N_    2048
#define C_    768
#define H_    12
#define HD_   64
#define NROWS (B_*N_)      // 4096
#define QKVC  (3*C_)       // 2304
#define EPSV  1e-6f
#define SCALE 0.125f       // 1/sqrt(HD)
#define LOG2E 1.44269504088896f
#define SMAX  12.0f        // static softmax max: logit*log2e <= 8*1.443+eps < 12

typedef unsigned short u16;
typedef short bf16x8 __attribute__((ext_vector_type(8)));   // 8 bf16 = 4 VGPRs
typedef float f32x4  __attribute__((ext_vector_type(4)));   // MFMA C/D

__device__ __forceinline__ float b2f(u16 u) {
    unsigned v = ((unsigned)u) << 16;
    return __builtin_bit_cast(float, v);
}
__device__ __forceinline__ u16 f2b(float f) {   // RNE
    unsigned u = __builtin_bit_cast(unsigned, f);
    u += 0x7fffu + ((u >> 16) & 1u);
    return (u16)(u >> 16);
}
__device__ __forceinline__ unsigned pk2(float a, float b) {
#if __has_builtin(__builtin_amdgcn_cvt_pk_bf16_f32)
    auto r = __builtin_amdgcn_cvt_pk_bf16_f32(a, b);
    return __builtin_bit_cast(unsigned, r);
#else
    return (unsigned)f2b(a) | ((unsigned)f2b(b) << 16);
#endif
}
__device__ __forceinline__ float fexp2(float x) {
#if __has_builtin(__builtin_amdgcn_exp2f)
    return __builtin_amdgcn_exp2f(x);
#else
    return exp2f(x);
#endif
}
// async global->LDS, 16B/lane; LDS dest = wave-uniform base + lane*16
__device__ __forceinline__ void gload_lds16(const void* g, void* l) {
    __builtin_amdgcn_global_load_lds(
        (const __attribute__((address_space(1))) unsigned int*)g,
        (__attribute__((address_space(3))) unsigned int*)l, 16, 0, 0);
}

// ---------------------------------------------------------------------------
// Fused prologue: [0,432) wtrans qkv_w, [432,576) wtrans proj_w,
// [576,3648) fp32->bf16 cvt of x. All independent; one launch instead of 3.
// Branch is block-uniform so the __syncthreads in wtrans is safe.
// ---------------------------------------------------------------------------
__device__ __forceinline__ void wtrans_body(const float* __restrict__ W,
                                            u16* __restrict__ Wt,
                                            int K, int N, int bx, int by,
                                            float (*T)[65]) {
    const int k0 = by * 64, n0 = bx * 64;
    const int t = threadIdx.x, r = t >> 6, c = t & 63;
#pragma unroll
    for (int p = 0; p < 16; ++p) {
        const int kl = p * 4 + r;
        T[kl][c] = W[(size_t)(k0 + kl) * N + n0 + c];
    }
    __syncthreads();
#pragma unroll
    for (int p = 0; p < 16; ++p) {
        const int nl = p * 4 + r;
        Wt[(size_t)(n0 + nl) * K + k0 + c] = f2b(T[c][nl]);
    }
}

__global__ __launch_bounds__(256)
void prep_kernel(const float* __restrict__ x, u16* __restrict__ xb,
                 const float* __restrict__ qkv_w, u16* __restrict__ qwt,
                 const float* __restrict__ proj_w, u16* __restrict__ pwt) {
    __shared__ float T[64][65];
    const int blk = blockIdx.x;
    if (blk < 432) {
        wtrans_body(qkv_w, qwt, C_, QKVC, blk % 36, blk / 36, T);
    } else if (blk < 576) {
        const int lin = blk - 432;
        wtrans_body(proj_w, pwt, C_, C_, lin % 12, lin / 12, T);
    } else {
        const int i = ((blk - 576) * 256 + threadIdx.x) * 4;
        const float4 v = *(const float4*)(x + i);
        uint2 o = { pk2(v.x, v.y), pk2(v.z, v.w) };
        *(uint2*)(xb + i) = o;
    }
}

// ---------------------------------------------------------------------------
// bf16 TN GEMM: C[M][N] = A[M][K] @ Bt[N][K]^T + bias
// 128xBN tile (BN=128 or 64), BK=32, 256 thr / 4 waves. LDS pitch 32 elem,
// 16B-chunk XOR swizzle (chunk ^= row&3) staged by inverting the swizzle on
// global addrs. XCD-chunked block remap (grid %8 == 0). BN=64 for the proj
// GEMM (N=768): 384 blocks vs 192.
// R6 LESSON: BK=64 (half the barriers, double the per-barrier staging)
// regressed 5% -- occupancy is VGPR-capped so extra LDS bought nothing and
// the longer vmcnt(0) drain cost more than the saved barriers. Keep BK=32.
// ---------------------------------------------------------------------------
template <bool BF16OUT, int BN>
__global__ __launch_bounds__(256)
void gemm_tn_kernel(const u16* __restrict__ A, const u16* __restrict__ Bt,
                    const float* __restrict__ bias, void* __restrict__ Cout,
                    int M, int N, int K) {
    constexpr int NB = BN / 32;                 // nb frags per wave
    __shared__ __attribute__((aligned(16))) u16 As[128 * 32];
    __shared__ __attribute__((aligned(16))) u16 Bs[BN * 32];
    const int tid = threadIdx.x;
    const int w = tid >> 6, l = tid & 63;
    const int lq = l & 15, quad = l >> 4;

    // XCD-chunked remap
    const int gx  = gridDim.x;
    const int nwg = gx * gridDim.y;
    const int d   = blockIdx.x + gx * blockIdx.y;
    const int lin = (d & 7) * (nwg >> 3) + (d >> 3);
    const int mbase = (lin / gx) * 128, nbase = (lin % gx) * BN;

    f32x4 acc[4][NB];
    const f32x4 z4 = {0.f, 0.f, 0.f, 0.f};
#pragma unroll
    for (int mb = 0; mb < 4; ++mb)
#pragma unroll
        for (int nb = 0; nb < NB; ++nb) acc[mb][nb] = z4;

    const int srow = (l >> 2);
    const int sdc  = (l & 3) ^ ((l >> 2) & 3);

    for (int k0 = 0; k0 < K; k0 += 32) {
#pragma unroll
        for (int cc = 0; cc < 2; ++cc) {        // A: 8 chunks, 2 per wave
            const int c = 2 * w + cc;
            const int row = 16 * c + srow;
            gload_lds16(A + (size_t)(mbase + row) * K + k0 + sdc * 8, &As[c * 512]);
        }
#pragma unroll
        for (int cc = 0; cc < BN / 64; ++cc) {  // B: BN/16 chunks
            const int c = (BN / 64) * w + cc;
            const int row = 16 * c + srow;
            gload_lds16(Bt + (size_t)(nbase + row) * K + k0 + sdc * 8, &Bs[c * 512]);
        }
        __syncthreads();

        bf16x8 af[4], bfr[NB];
#pragma unroll
        for (int mb = 0; mb < 4; ++mb)
            af[mb] = *(const bf16x8*)
                &As[((w >> 1) * 64 + mb * 16 + lq) * 32 + ((quad ^ (lq & 3)) * 8)];
#pragma unroll
        for (int nb = 0; nb < NB; ++nb)
            bfr[nb] = *(const bf16x8*)
                &Bs[((w & 1) * (BN / 2) + nb * 16 + lq) * 32 + ((quad ^ (lq & 3)) * 8)];
#pragma unroll
        for (int mb = 0; mb < 4; ++mb)
#pragma unroll
            for (int nb = 0; nb < NB; ++nb)
                acc[mb][nb] = __builtin_amdgcn_mfma_f32_16x16x32_bf16(
                    af[mb], bfr[nb], acc[mb][nb], 0, 0, 0);
        __syncthreads();
    }

#pragma unroll
    for (int nb = 0; nb < NB; ++nb) {
        const int col = nbase + (w & 1) * (BN / 2) + nb * 16 + lq;
        const float bv = bias[col];
#pragma unroll
        for (int mb = 0; mb < 4; ++mb) {
#pragma unroll
            for (int r = 0; r < 4; ++r) {
                const int row = mbase + (w >> 1) * 64 + mb * 16 + quad * 4 + r;
                const float v = acc[mb][nb][r] + bv;
                if (BF16OUT) ((u16*)Cout)[(size_t)row * N + col] = f2b(v);
                else         ((float*)Cout)[(size_t)row * N + col] = v;
            }
        }
    }
}

// ---------------------------------------------------------------------------
// Fused normrope + vpack (independent regions of qkvb): [0,768) vpack
// (heavier blocks first), [768,3840) normrope. One launch instead of 2.
//
// normrope: RMSNorm + RoPE. 16 lanes per (row,h), ushort4 per lane.
// q (roped, *SCALE*LOG2E) -> back into qkv buffer.
// k (roped)               -> kpack, MFMA-A-fragment-packed tiles:
//   tile(bh,kt) base = (bh*32+kt)*4096 ; elem ((kb*2+ks)*64 + lane)*8 + j
//   where lane=(quad*16+m), K[key=kb*16+m][d=ks*32+quad*8+j].
// vpack: qkv V-region -> vpack, MFMA-A-fragment-packed V^T tiles.
// ---------------------------------------------------------------------------
__device__ __forceinline__ void normrope_body(
        u16* __restrict__ qkv, u16* __restrict__ kpack,
        const float* __restrict__ cosb, const float* __restrict__ sinb,
        const float* __restrict__ qw, const float* __restrict__ kw,
        int blk) {
    const int item = blk * 16 + (threadIdx.x >> 4); // (b*N+n)*H + h
    const int lq   = threadIdx.x & 15;
    const int h    = item % H_;
    const int row  = item / H_;        // b*N + n
    const int n    = row & (N_ - 1);
    const int b    = row >> 11;
    const size_t base = (size_t)row * QKVC + h * HD_ + lq * 4;

    const ushort4 q4 = *(const ushort4*)&qkv[base];
    const ushort4 k4 = *(const ushort4*)&qkv[base + C_];
    float qf[4], kf[4];
    qf[0] = b2f(q4.x); qf[1] = b2f(q4.y); qf[2] = b2f(q4.z); qf[3] = b2f(q4.w);
    kf[0] = b2f(k4.x); kf[1] = b2f(k4.y); kf[2] = b2f(k4.z); kf[3] = b2f(k4.w);

    float q2 = qf[0]*qf[0] + qf[1]*qf[1] + qf[2]*qf[2] + qf[3]*qf[3];
    float k2 = kf[0]*kf[0] + kf[1]*kf[1] + kf[2]*kf[2] + kf[3]*kf[3];
#pragma unroll
    for (int off = 8; off >= 1; off >>= 1) {
        q2 += __shfl_xor(q2, off, 64);
        k2 += __shfl_xor(k2, off, 64);
    }
    const float rq = rsqrtf(q2 * (1.f / 64.f) + EPSV);
    const float rk = rsqrtf(k2 * (1.f / 64.f) + EPSV);

    const float4 qwv = *(const float4*)&qw[lq * 4];
    const float4 kwv = *(const float4*)&kw[lq * 4];
    const float4 cv  = *(const float4*)&cosb[n * HD_ + lq * 4];
    const float4 sv  = *(const float4*)&sinb[n * HD_ + lq * 4];

    float qn[4], kn[4];
    qn[0] = qf[0]*rq*qwv.x; qn[1] = qf[1]*rq*qwv.y;
    qn[2] = qf[2]*rq*qwv.z; qn[3] = qf[3]*rq*qwv.w;
    kn[0] = kf[0]*rk*kwv.x; kn[1] = kf[1]*rk*kwv.y;
    kn[2] = kf[2]*rk*kwv.z; kn[3] = kf[3]*rk*kwv.w;

    const float sgn = (lq < 8) ? -1.f : 1.f;   // partner lane = lq^8 (d +/- 32)
    float qo[4], ko[4];
    const float cc[4] = {cv.x, cv.y, cv.z, cv.w};
    const float ss[4] = {sv.x, sv.y, sv.z, sv.w};
#pragma unroll
    for (int j = 0; j < 4; ++j) {
        const float qp = __shfl_xor(qn[j], 8, 64);
        const float kp = __shfl_xor(kn[j], 8, 64);
        qo[j] = (qn[j] * cc[j] + sgn * qp * ss[j]) * (SCALE * LOG2E);
        ko[j] =  kn[j] * cc[j] + sgn * kp * ss[j];
    }
    uint2 qout = { pk2(qo[0], qo[1]), pk2(qo[2], qo[3]) };
    uint2 kout = { pk2(ko[0], ko[1]), pk2(ko[2], ko[3]) };
    *(uint2*)&qkv[base] = qout;

    // k -> fragment-packed tile
    const int kt = n >> 6, kr = n & 63;
    const int kb = kr >> 4, m = kr & 15;
    const int ks = lq >> 3, quad = (lq >> 1) & 3, jj = (lq & 1) * 4;
    const size_t off = ((size_t)(b * H_ + h) * 32 + kt) * 4096
                     + (size_t)((kb * 2 + ks) * 64 + quad * 16 + m) * 8 + jj;
    *(uint2*)&kpack[off] = kout;
}

__device__ __forceinline__ void vpack_body(
        const u16* __restrict__ qkv, u16* __restrict__ vpack,
        int kt, int bh, u16 (*Tv)[72]) {
    const int b = bh / H_, h = bh % H_;
    const int t = threadIdx.x;
    {
        const int r = t >> 2, seg = t & 3;   // row=key, 16 u16 per thread
        const u16* src = &qkv[(size_t)(b * N_ + kt * 64 + r) * QKVC
                              + 2 * C_ + h * HD_ + seg * 16];
        const uint4 v0 = *(const uint4*)src;
        const uint4 v1 = *(const uint4*)(src + 8);
        *(uint4*)&Tv[r][seg * 16]     = v0;
        *(uint4*)&Tv[r][seg * 16 + 8] = v1;
    }
    __syncthreads();
    u16 tmp[16];
#pragma unroll
    for (int g2 = 0; g2 < 2; ++g2) {
        const int g = t * 2 + g2;            // j-group 0..511
        const int mbks = g >> 6;             // (mb*2+ks)
        const int l  = g & 63;
        const int mb = mbks >> 1, ks = mbks & 1;
        const int m  = l & 15,  quad = l >> 4;
#pragma unroll
        for (int j = 0; j < 8; ++j)
            tmp[g2 * 8 + j] = Tv[ks * 32 + quad * 8 + j][mb * 16 + m];
    }
    u16* dst = &vpack[((size_t)bh * 32 + kt) * 4096 + t * 16];
    *(uint4*)dst       = *(const uint4*)&tmp[0];
    *(uint4*)(dst + 8) = *(const uint4*)&tmp[8];
}

__global__ __launch_bounds__(256)
void normvpack_kernel(u16* __restrict__ qkv, u16* __restrict__ kpack,
                      u16* __restrict__ vpack,
                      const float* __restrict__ cosb,
                      const float* __restrict__ sinb,
                      const float* __restrict__ qw,
                      const float* __restrict__ kw) {
    __shared__ u16 Tv[64][72];
    const int blk = blockIdx.x;
    if (blk < 768) {
        vpack_body(qkv, vpack, blk & 31, blk >> 5, Tv);
    } else {
        normrope_body(qkv, kpack, cosb, sinb, qw, kw, blk - 768);
    }
}

// ---------------------------------------------------------------------------
// MFMA flash attention -- R8: 4-wave blocks over the SAME 64 queries (nq=4),
// wave w handles keys kt = 4*kt2+w (8 iterations). Rationale: flash was
// pinned at ~45us across occupancy/schedule changes; invariant = L2 traffic
// (786 MB/dispatch at QB=32 = ~50% of pure-L2 feed). QB=64 at FULL occupancy
// (768 blocks x 4 waves = 12 waves/CU, same as before) halves L2 traffic
// while doubling arithmetic intensity per 16KB K/V visit.
// Static-max softmax (SMAX) => additive partials; sequential 4-way combine:
// w3 writes Oex/lex, w2/w1 add (barrier-separated), w0 finalizes.
// LDS 49.4KB -> 3 blocks/CU. Per-wave structure = R0's proven 116-VGPR shape.
// R4 LESSON: no K double-buffer (spilled). setprio: R2 measured -12%.
// ---------------------------------------------------------------------------
#define NQ_   4                 // 16-row q sub-tiles per block
#define QB_   (NQ_ * 16)        // 64 queries per block
#define NQT_  (N_ / QB_)        // 32 q-tiles per bh

__global__ __launch_bounds__(256, 3)
void flash_mfma_kernel(const u16* __restrict__ qkv,
                       const u16* __restrict__ kpack,
                       const u16* __restrict__ vpack,
                       u16* __restrict__ attnb) {
    __shared__ __attribute__((aligned(16))) u16 Ps[4][QB_ * 64];  // per-wave P
    __shared__ __attribute__((aligned(16))) float Oex[QB_ * 64];  // exchange
    __shared__ float lex[QB_];

    const int tid = threadIdx.x;
    const int w = tid >> 6, l = tid & 63;
    const int lq = l & 15, quad = l >> 4;
    const int sw = lq & 7;                 // P-row swizzle key

    // XCD-pinned remap: xcd = lin&7 owns bh {3x..3x+2}; NQT_ q-tiles per bh.
    const int lin  = blockIdx.x;
    const int slot = lin >> 3;                        // 0..95
    const int bh   = (lin & 7) * 3 + (slot / NQT_);   // 0..23
    const int qt   = slot & (NQT_ - 1);               // 64-query tile
    const int b = bh / H_, h = bh % H_;
    const size_t qbase = (size_t)b * N_ * QKVC + h * HD_;
    const size_t tbase = (size_t)bh * 32 * 4096;    // packed-tile base for bh

    // Q B-frags (all 4 waves: same QB_ queries)
    bf16x8 qb[NQ_][2];
#pragma unroll
    for (int nq = 0; nq < NQ_; ++nq)
#pragma unroll
        for (int ks = 0; ks < 2; ++ks)
            qb[nq][ks] = *(const bf16x8*)
                &qkv[qbase + (size_t)(qt * QB_ + nq * 16 + lq) * QKVC
                     + ks * 32 + quad * 8];

    float lsum[NQ_];
#pragma unroll
    for (int nq = 0; nq < NQ_; ++nq) lsum[nq] = 0.f;
    f32x4 oacc[4][NQ_];
    const f32x4 z4 = {0.f, 0.f, 0.f, 0.f};
#pragma unroll
    for (int mb = 0; mb < 4; ++mb)
#pragma unroll
        for (int nq = 0; nq < NQ_; ++nq) oacc[mb][nq] = z4;

    // preload K frags for first key tile (kt = w); fully coalesced 1KB loads
    bf16x8 ka[4][2];
#pragma unroll
    for (int kb = 0; kb < 4; ++kb)
#pragma unroll
        for (int ks = 0; ks < 2; ++ks)
            ka[kb][ks] = *(const bf16x8*)
                &kpack[tbase + (size_t)w * 4096 + ((kb * 2 + ks) * 64 + l) * 8];

    for (int kt2 = 0; kt2 < 8; ++kt2) {
        const int kt  = 4 * kt2 + w;
        const int ktn = (kt + 4) & 31;       // prefetch target (wrap harmless)
        const size_t vb = tbase + (size_t)kt * 4096;
        const size_t kb_n = tbase + (size_t)ktn * 4096;

        // V frags — issued early, consumed at PV below
        bf16x8 va[4][2];
#pragma unroll
        for (int mb = 0; mb < 4; ++mb)
#pragma unroll
            for (int ks = 0; ks < 2; ++ks)
                va[mb][ks] = *(const bf16x8*)
                    &vpack[vb + ((mb * 2 + ks) * 64 + l) * 8];

        // per-kb: S-MFMAs -> exp2 -> P-write (keeps sacc lifetime short)
#pragma unroll
        for (int kb = 0; kb < 4; ++kb) {
            f32x4 sacc[NQ_];
#pragma unroll
            for (int nq = 0; nq < NQ_; ++nq) sacc[nq] = z4;
            __builtin_amdgcn_s_setprio(1);
#pragma unroll
            for (int ks = 0; ks < 2; ++ks)
#pragma unroll
                for (int nq = 0; nq < NQ_; ++nq)
                    sacc[nq] = __builtin_amdgcn_mfma_f32_16x16x32_bf16(
                        ka[kb][ks], qb[nq][ks], sacc[nq], 0, 0, 0);
            __builtin_amdgcn_s_setprio(0);
#pragma unroll
            for (int nq = 0; nq < NQ_; ++nq) {
                float p[4];
#pragma unroll
                for (int r = 0; r < 4; ++r) p[r] = fexp2(sacc[nq][r] - SMAX);
                lsum[nq] += (p[0] + p[1]) + (p[2] + p[3]);
                uint2 pkv = { pk2(p[0], p[1]), pk2(p[2], p[3]) };
                *(uint2*)&Ps[w][(nq * 16 + lq) * 64
                                + (((kb * 2 + (quad >> 1)) ^ sw) * 8)
                                + (quad & 1) * 4] = pkv;
            }
        }

        // prefetch next K tile IN-PLACE (after all S-MFMAs consumed ka)
#pragma unroll
        for (int kb = 0; kb < 4; ++kb)
#pragma unroll
            for (int ks = 0; ks < 2; ++ks)
                ka[kb][ks] = *(const bf16x8*)
                    &kpack[kb_n + ((kb * 2 + ks) * 64 + l) * 8];

        // P B-frags (same-wave LDS RAW: DS-pipe ordered, no barrier)
        bf16x8 pb[2][NQ_];
#pragma unroll
        for (int ks = 0; ks < 2; ++ks)
#pragma unroll
            for (int nq = 0; nq < NQ_; ++nq)
                pb[ks][nq] = *(const bf16x8*)
                    &Ps[w][(nq * 16 + lq) * 64 + (((ks * 4 + quad) ^ sw) * 8)];

        // O^T += V^T.P^T
        __builtin_amdgcn_s_setprio(1);
#pragma unroll
        for (int mb = 0; mb < 4; ++mb)
#pragma unroll
            for (int ks = 0; ks < 2; ++ks)
#pragma unroll
                for (int nq = 0; nq < NQ_; ++nq)
                    oacc[mb][nq] = __builtin_amdgcn_mfma_f32_16x16x32_bf16(
                        va[mb][ks], pb[ks][nq], oacc[mb][nq], 0, 0, 0);
        __builtin_amdgcn_s_setprio(0);
    }

    // finish l: reduce over quad groups
#pragma unroll
    for (int nq = 0; nq < NQ_; ++nq) {
        lsum[nq] += __shfl_xor(lsum[nq], 16, 64);
        lsum[nq] += __shfl_xor(lsum[nq], 32, 64);
    }

    // 4-way combine: w3 writes, w2/w1 add, w0 finalizes (barrier-separated).
    // Chunk addresses are disjoint across lanes (chunk = (mb*4+quad)^lq).
    if (w == 3) {
#pragma unroll
        for (int nq = 0; nq < NQ_; ++nq) {
#pragma unroll
            for (int mb = 0; mb < 4; ++mb) {
                const int chunk = (mb * 4 + quad) ^ lq;
                *(float4*)&Oex[(nq * 16 + lq) * 64 + chunk * 4] =
                    *(float4*)&oacc[mb][nq];
            }
            if (quad == 0) lex[nq * 16 + lq] = lsum[nq];
        }
    }
    __syncthreads();
    if (w == 2) {
#pragma unroll
        for (int nq = 0; nq < NQ_; ++nq) {
#pragma unroll
            for (int mb = 0; mb < 4; ++mb) {
                const int chunk = (mb * 4 + quad) ^ lq;
                float4* p = (float4*)&Oex[(nq * 16 + lq) * 64 + chunk * 4];
                float4 t = *p;
                t.x += oacc[mb][nq][0]; t.y += oacc[mb][nq][1];
                t.z += oacc[mb][nq][2]; t.w += oacc[mb][nq][3];
                *p = t;
            }
            if (quad == 0) lex[nq * 16 + lq] += lsum[nq];
        }
    }
    __syncthreads();
    if (w == 1) {
#pragma unroll
        for (int nq = 0; nq < NQ_; ++nq) {
#pragma unroll
            for (int mb = 0; mb < 4; ++mb) {
                const int chunk = (mb * 4 + quad) ^ lq;
                float4* p = (float4*)&Oex[(nq * 16 + lq) * 64 + chunk * 4];
                float4 t = *p;
                t.x += oacc[mb][nq][0]; t.y += oacc[mb][nq][1];
                t.z += oacc[mb][nq][2]; t.w += oacc[mb][nq][3];
                *p = t;
            }
            if (quad == 0) lex[nq * 16 + lq] += lsum[nq];
        }
    }
    __syncthreads();
    if (w == 0) {
#pragma unroll
        for (int nq = 0; nq < NQ_; ++nq) {
            const int qrow = nq * 16 + lq;
            const float inv = 1.f / (lsum[nq] + lex[qrow]);
#pragma unroll
            for (int mb = 0; mb < 4; ++mb) {
                const int chunk = (mb * 4 + quad) ^ lq;
                const float4 oe = *(const float4*)&Oex[qrow * 64 + chunk * 4];
                const float o0 = (oacc[mb][nq][0] + oe.x) * inv;
                const float o1 = (oacc[mb][nq][1] + oe.y) * inv;
                const float o2 = (oacc[mb][nq][2] + oe.z) * inv;
                const float o3 = (oacc[mb][nq][3] + oe.w) * inv;
                uint2 ov = { pk2(o0, o1), pk2(o2, o3) };
                *(uint2*)&Ps[0][qrow * 64
                                + (((mb * 2 + (quad >> 1)) ^ sw) * 8)
                                + (quad & 1) * 4] = ov;
            }
        }
        // coalesced 16B stores of QB_ q x 64 dv
#pragma unroll
        for (int pass = 0; pass < QB_ / 8; ++pass) {
            const int ql = pass * 8 + (l >> 3);          // 0..QB_-1
            const int c  = l & 7;                        // dv chunk
            const bf16x8 v = *(const bf16x8*)&Ps[0][ql * 64 + ((c ^ (ql & 7)) * 8)];
            const int query = qt * QB_ + ql;
            *(bf16x8*)&attnb[(size_t)(b * N_ + query) * C_ + h * HD_ + c * 8] = v;
        }
    }
}

// ---------------------------------------------------------------------------
extern "C" void kernel_launch(void* const* d_in, const int* in_sizes, int n_in,
                              void* d_out, int out_size, void* d_ws, size_t ws_size,
                              hipStream_t stream) {
    const float* x        = (const float*)d_in[0];
    const float* rope_cos = (const float*)d_in[1];
    const float* rope_sin = (const float*)d_in[2];
    const float* qkv_w    = (const float*)d_in[3];
    const float* qkv_b    = (const float*)d_in[4];
    const float* proj_w   = (const float*)d_in[5];
    const float* proj_b   = (const float*)d_in[6];
    const float* q_nw     = (const float*)d_in[7];
    const float* k_nw     = (const float*)d_in[8];
    float* out = (float*)d_out;

    // ws layout (bf16 buffers), ~42.5 MB. kpackb ALIASES xb: xb is dead after
    // gemm1; normvpack (writes kpackb) runs after gemm1 on the same stream.
    u16* xb    = (u16*)d_ws;                               // 4096x768
    u16* qwt   = xb    + (size_t)NROWS * C_;               // 2304x768 (W^T)
    u16* pwt   = qwt   + (size_t)QKVC * C_;                // 768x768  (W^T)
    u16* qkvb  = pwt   + (size_t)C_ * C_;                  // 4096x2304
    u16* vpackb= qkvb  + (size_t)NROWS * QKVC;             // 24x32x4096
    u16* attnb = vpackb+ (size_t)B_ * H_ * 32 * 4096;      // 4096x768
    u16* kpackb= xb;                                       // 24x32x4096 (alias)

    prep_kernel<<<dim3(576 + NROWS * C_ / 1024), 256, 0, stream>>>(
        x, xb, qkv_w, qwt, proj_w, pwt);

    gemm_tn_kernel<true, 128><<<dim3(QKVC / 128, NROWS / 128), 256, 0, stream>>>(
        xb, qwt, qkv_b, qkvb, NROWS, QKVC, C_);

    normvpack_kernel<<<dim3(768 + NROWS * H_ / 16), 256, 0, stream>>>(
        qkvb, kpackb, vpackb, rope_cos, rope_sin, q_nw, k_nw);

    flash_mfma_kernel<<<dim3(B_ * H_ * NQT_), 256, 0, stream>>>(
        qkvb, kpackb, vpackb, attnb);

    gemm_tn_kernel<false, 64><<<dim3(C_ / 64, NROWS / 128), 256, 0, stream>>>(
        attnb, pwt, proj_b, out, NROWS, C_, C_);
}

// Round 9
// 176.368 us; speedup vs baseline: 1.5052x; 1.5052x over previous
//
#include <hip/hip_runtime.h>
#include <math.h>

#define B_    2
#define N_    2048
#define C_    768
#define H_    12
#define HD_   64
#define NROWS (B_*N_)      // 4096
#define QKVC  (3*C_)       // 2304
#define EPSV  1e-6f
#define SCALE 0.125f       // 1/sqrt(HD)
#define LOG2E 1.44269504088896f
#define SMAX  12.0f        // static softmax max: logit*log2e <= 8*1.443+eps < 12

typedef unsigned short u16;
typedef short bf16x8 __attribute__((ext_vector_type(8)));   // 8 bf16 = 4 VGPRs
typedef float f32x4  __attribute__((ext_vector_type(4)));   // MFMA C/D

__device__ __forceinline__ float b2f(u16 u) {
    unsigned v = ((unsigned)u) << 16;
    return __builtin_bit_cast(float, v);
}
__device__ __forceinline__ u16 f2b(float f) {   // RNE
    unsigned u = __builtin_bit_cast(unsigned, f);
    u += 0x7fffu + ((u >> 16) & 1u);
    return (u16)(u >> 16);
}
__device__ __forceinline__ unsigned pk2(float a, float b) {
#if __has_builtin(__builtin_amdgcn_cvt_pk_bf16_f32)
    auto r = __builtin_amdgcn_cvt_pk_bf16_f32(a, b);
    return __builtin_bit_cast(unsigned, r);
#else
    return (unsigned)f2b(a) | ((unsigned)f2b(b) << 16);
#endif
}
__device__ __forceinline__ float fexp2(float x) {
#if __has_builtin(__builtin_amdgcn_exp2f)
    return __builtin_amdgcn_exp2f(x);
#else
    return exp2f(x);
#endif
}
// async global->LDS, 16B/lane; LDS dest = wave-uniform base + lane*16
__device__ __forceinline__ void gload_lds16(const void* g, void* l) {
    __builtin_amdgcn_global_load_lds(
        (const __attribute__((address_space(1))) unsigned int*)g,
        (__attribute__((address_space(3))) unsigned int*)l, 16, 0, 0);
}

// ---------------------------------------------------------------------------
// Fused prologue: [0,432) wtrans qkv_w, [432,576) wtrans proj_w,
// [576,3648) fp32->bf16 cvt of x. All independent; one launch instead of 3.
// Branch is block-uniform so the __syncthreads in wtrans is safe.
// ---------------------------------------------------------------------------
__device__ __forceinline__ void wtrans_body(const float* __restrict__ W,
                                            u16* __restrict__ Wt,
                                            int K, int N, int bx, int by,
                                            float (*T)[65]) {
    const int k0 = by * 64, n0 = bx * 64;
    const int t = threadIdx.x, r = t >> 6, c = t & 63;
#pragma unroll
    for (int p = 0; p < 16; ++p) {
        const int kl = p * 4 + r;
        T[kl][c] = W[(size_t)(k0 + kl) * N + n0 + c];
    }
    __syncthreads();
#pragma unroll
    for (int p = 0; p < 16; ++p) {
        const int nl = p * 4 + r;
        Wt[(size_t)(n0 + nl) * K + k0 + c] = f2b(T[c][nl]);
    }
}

__global__ __launch_bounds__(256)
void prep_kernel(const float* __restrict__ x, u16* __restrict__ xb,
                 const float* __restrict__ qkv_w, u16* __restrict__ qwt,
                 const float* __restrict__ proj_w, u16* __restrict__ pwt) {
    __shared__ float T[64][65];
    const int blk = blockIdx.x;
    if (blk < 432) {
        wtrans_body(qkv_w, qwt, C_, QKVC, blk % 36, blk / 36, T);
    } else if (blk < 576) {
        const int lin = blk - 432;
        wtrans_body(proj_w, pwt, C_, C_, lin % 12, lin / 12, T);
    } else {
        const int i = ((blk - 576) * 256 + threadIdx.x) * 4;
        const float4 v = *(const float4*)(x + i);
        uint2 o = { pk2(v.x, v.y), pk2(v.z, v.w) };
        *(uint2*)(xb + i) = o;
    }
}

// ---------------------------------------------------------------------------
// bf16 TN GEMM: C[M][N] = A[M][K] @ Bt[N][K]^T + bias
// 128xBN tile (BN=128 or 64), BK=32, 256 thr / 4 waves. LDS pitch 32 elem,
// 16B-chunk XOR swizzle (chunk ^= row&3) staged by inverting the swizzle on
// global addrs. XCD-chunked block remap (grid %8 == 0). BN=64 for the proj
// GEMM (N=768): 384 blocks vs 192.
// R6 LESSON: BK=64 (half the barriers, double the per-barrier staging)
// regressed 5% -- occupancy is VGPR-capped so extra LDS bought nothing and
// the longer vmcnt(0) drain cost more than the saved barriers. Keep BK=32.
// ---------------------------------------------------------------------------
template <bool BF16OUT, int BN>
__global__ __launch_bounds__(256)
void gemm_tn_kernel(const u16* __restrict__ A, const u16* __restrict__ Bt,
                    const float* __restrict__ bias, void* __restrict__ Cout,
                    int M, int N, int K) {
    constexpr int NB = BN / 32;                 // nb frags per wave
    __shared__ __attribute__((aligned(16))) u16 As[128 * 32];
    __shared__ __attribute__((aligned(16))) u16 Bs[BN * 32];
    const int tid = threadIdx.x;
    const int w = tid >> 6, l = tid & 63;
    const int lq = l & 15, quad = l >> 4;

    // XCD-chunked remap
    const int gx  = gridDim.x;
    const int nwg = gx * gridDim.y;
    const int d   = blockIdx.x + gx * blockIdx.y;
    const int lin = (d & 7) * (nwg >> 3) + (d >> 3);
    const int mbase = (lin / gx) * 128, nbase = (lin % gx) * BN;

    f32x4 acc[4][NB];
    const f32x4 z4 = {0.f, 0.f, 0.f, 0.f};
#pragma unroll
    for (int mb = 0; mb < 4; ++mb)
#pragma unroll
        for (int nb = 0; nb < NB; ++nb) acc[mb][nb] = z4;

    const int srow = (l >> 2);
    const int sdc  = (l & 3) ^ ((l >> 2) & 3);

    for (int k0 = 0; k0 < K; k0 += 32) {
#pragma unroll
        for (int cc = 0; cc < 2; ++cc) {        // A: 8 chunks, 2 per wave
            const int c = 2 * w + cc;
            const int row = 16 * c + srow;
            gload_lds16(A + (size_t)(mbase + row) * K + k0 + sdc * 8, &As[c * 512]);
        }
#pragma unroll
        for (int cc = 0; cc < BN / 64; ++cc) {  // B: BN/16 chunks
            const int c = (BN / 64) * w + cc;
            const int row = 16 * c + srow;
            gload_lds16(Bt + (size_t)(nbase + row) * K + k0 + sdc * 8, &Bs[c * 512]);
        }
        __syncthreads();

        bf16x8 af[4], bfr[NB];
#pragma unroll
        for (int mb = 0; mb < 4; ++mb)
            af[mb] = *(const bf16x8*)
                &As[((w >> 1) * 64 + mb * 16 + lq) * 32 + ((quad ^ (lq & 3)) * 8)];
#pragma unroll
        for (int nb = 0; nb < NB; ++nb)
            bfr[nb] = *(const bf16x8*)
                &Bs[((w & 1) * (BN / 2) + nb * 16 + lq) * 32 + ((quad ^ (lq & 3)) * 8)];
#pragma unroll
        for (int mb = 0; mb < 4; ++mb)
#pragma unroll
            for (int nb = 0; nb < NB; ++nb)
                acc[mb][nb] = __builtin_amdgcn_mfma_f32_16x16x32_bf16(
                    af[mb], bfr[nb], acc[mb][nb], 0, 0, 0);
        __syncthreads();
    }

#pragma unroll
    for (int nb = 0; nb < NB; ++nb) {
        const int col = nbase + (w & 1) * (BN / 2) + nb * 16 + lq;
        const float bv = bias[col];
#pragma unroll
        for (int mb = 0; mb < 4; ++mb) {
#pragma unroll
            for (int r = 0; r < 4; ++r) {
                const int row = mbase + (w >> 1) * 64 + mb * 16 + quad * 4 + r;
                const float v = acc[mb][nb][r] + bv;
                if (BF16OUT) ((u16*)Cout)[(size_t)row * N + col] = f2b(v);
                else         ((float*)Cout)[(size_t)row * N + col] = v;
            }
        }
    }
}

// ---------------------------------------------------------------------------
// Fused normrope + vpack (independent regions of qkvb): [0,768) vpack
// (heavier blocks first), [768,3840) normrope. One launch instead of 2.
//
// normrope: RMSNorm + RoPE. 16 lanes per (row,h), ushort4 per lane.
// q (roped, *SCALE*LOG2E) -> back into qkv buffer.
// k (roped)               -> kpack, MFMA-A-fragment-packed tiles:
//   tile(bh,kt) base = (bh*32+kt)*4096 ; elem ((kb*2+ks)*64 + lane)*8 + j
//   where lane=(quad*16+m), K[key=kb*16+m][d=ks*32+quad*8+j].
// vpack: qkv V-region -> vpack, MFMA-A-fragment-packed V^T tiles.
// ---------------------------------------------------------------------------
__device__ __forceinline__ void normrope_body(
        u16* __restrict__ qkv, u16* __restrict__ kpack,
        const float* __restrict__ cosb, const float* __restrict__ sinb,
        const float* __restrict__ qw, const float* __restrict__ kw,
        int blk) {
    const int item = blk * 16 + (threadIdx.x >> 4); // (b*N+n)*H + h
    const int lq   = threadIdx.x & 15;
    const int h    = item % H_;
    const int row  = item / H_;        // b*N + n
    const int n    = row & (N_ - 1);
    const int b    = row >> 11;
    const size_t base = (size_t)row * QKVC + h * HD_ + lq * 4;

    const ushort4 q4 = *(const ushort4*)&qkv[base];
    const ushort4 k4 = *(const ushort4*)&qkv[base + C_];
    float qf[4], kf[4];
    qf[0] = b2f(q4.x); qf[1] = b2f(q4.y); qf[2] = b2f(q4.z); qf[3] = b2f(q4.w);
    kf[0] = b2f(k4.x); kf[1] = b2f(k4.y); kf[2] = b2f(k4.z); kf[3] = b2f(k4.w);

    float q2 = qf[0]*qf[0] + qf[1]*qf[1] + qf[2]*qf[2] + qf[3]*qf[3];
    float k2 = kf[0]*kf[0] + kf[1]*kf[1] + kf[2]*kf[2] + kf[3]*kf[3];
#pragma unroll
    for (int off = 8; off >= 1; off >>= 1) {
        q2 += __shfl_xor(q2, off, 64);
        k2 += __shfl_xor(k2, off, 64);
    }
    const float rq = rsqrtf(q2 * (1.f / 64.f) + EPSV);
    const float rk = rsqrtf(k2 * (1.f / 64.f) + EPSV);

    const float4 qwv = *(const float4*)&qw[lq * 4];
    const float4 kwv = *(const float4*)&kw[lq * 4];
    const float4 cv  = *(const float4*)&cosb[n * HD_ + lq * 4];
    const float4 sv  = *(const float4*)&sinb[n * HD_ + lq * 4];

    float qn[4], kn[4];
    qn[0] = qf[0]*rq*qwv.x; qn[1] = qf[1]*rq*qwv.y;
    qn[2] = qf[2]*rq*qwv.z; qn[3] = qf[3]*rq*qwv.w;
    kn[0] = kf[0]*rk*kwv.x; kn[1] = kf[1]*rk*kwv.y;
    kn[2] = kf[2]*rk*kwv.z; kn[3] = kf[3]*rk*kwv.w;

    const float sgn = (lq < 8) ? -1.f : 1.f;   // partner lane = lq^8 (d +/- 32)
    float qo[4], ko[4];
    const float cc[4] = {cv.x, cv.y, cv.z, cv.w};
    const float ss[4] = {sv.x, sv.y, sv.z, sv.w};
#pragma unroll
    for (int j = 0; j < 4; ++j) {
        const float qp = __shfl_xor(qn[j], 8, 64);
        const float kp = __shfl_xor(kn[j], 8, 64);
        qo[j] = (qn[j] * cc[j] + sgn * qp * ss[j]) * (SCALE * LOG2E);
        ko[j] =  kn[j] * cc[j] + sgn * kp * ss[j];
    }
    uint2 qout = { pk2(qo[0], qo[1]), pk2(qo[2], qo[3]) };
    uint2 kout = { pk2(ko[0], ko[1]), pk2(ko[2], ko[3]) };
    *(uint2*)&qkv[base] = qout;

    // k -> fragment-packed tile
    const int kt = n >> 6, kr = n & 63;
    const int kb = kr >> 4, m = kr & 15;
    const int ks = lq >> 3, quad = (lq >> 1) & 3, jj = (lq & 1) * 4;
    const size_t off = ((size_t)(b * H_ + h) * 32 + kt) * 4096
                     + (size_t)((kb * 2 + ks) * 64 + quad * 16 + m) * 8 + jj;
    *(uint2*)&kpack[off] = kout;
}

__device__ __forceinline__ void vpack_body(
        const u16* __restrict__ qkv, u16* __restrict__ vpack,
        int kt, int bh, u16 (*Tv)[72]) {
    const int b = bh / H_, h = bh % H_;
    const int t = threadIdx.x;
    {
        const int r = t >> 2, seg = t & 3;   // row=key, 16 u16 per thread
        const u16* src = &qkv[(size_t)(b * N_ + kt * 64 + r) * QKVC
                              + 2 * C_ + h * HD_ + seg * 16];
        const uint4 v0 = *(const uint4*)src;
        const uint4 v1 = *(const uint4*)(src + 8);
        *(uint4*)&Tv[r][seg * 16]     = v0;
        *(uint4*)&Tv[r][seg * 16 + 8] = v1;
    }
    __syncthreads();
    u16 tmp[16];
#pragma unroll
    for (int g2 = 0; g2 < 2; ++g2) {
        const int g = t * 2 + g2;            // j-group 0..511
        const int mbks = g >> 6;             // (mb*2+ks)
        const int l  = g & 63;
        const int mb = mbks >> 1, ks = mbks & 1;
        const int m  = l & 15,  quad = l >> 4;
#pragma unroll
        for (int j = 0; j < 8; ++j)
            tmp[g2 * 8 + j] = Tv[ks * 32 + quad * 8 + j][mb * 16 + m];
    }
    u16* dst = &vpack[((size_t)bh * 32 + kt) * 4096 + t * 16];
    *(uint4*)dst       = *(const uint4*)&tmp[0];
    *(uint4*)(dst + 8) = *(const uint4*)&tmp[8];
}

__global__ __launch_bounds__(256)
void normvpack_kernel(u16* __restrict__ qkv, u16* __restrict__ kpack,
                      u16* __restrict__ vpack,
                      const float* __restrict__ cosb,
                      const float* __restrict__ sinb,
                      const float* __restrict__ qw,
                      const float* __restrict__ kw) {
    __shared__ u16 Tv[64][72];
    const int blk = blockIdx.x;
    if (blk < 768) {
        vpack_body(qkv, vpack, blk & 31, blk >> 5, Tv);
    } else {
        normrope_body(qkv, kpack, cosb, sinb, qw, kw, blk - 768);
    }
}

// ---------------------------------------------------------------------------
// MFMA flash attention -- QB=64 / 4-wave blocks (nq=4), wave w handles keys
// kt = 4*kt2+w (8 iterations). Halves L2 K/V traffic vs QB=32 at the same
// waves/CU. Static-max softmax (SMAX) => additive partials; sequential 4-way
// combine (w3 writes, w2/w1 add, w0 finalizes, barrier-separated).
// R8 LESSON: __launch_bounds__(256,3) forced a 170-VGPR cap the 4-wave
// epilogue couldn't meet -> 295MB scratch spill, 133us. Use (256,2): 256-VGPR
// cap, natural alloc ~116-130, no spill; occupancy then set by VGPR/LDS.
// Oex ALIASES Ps[2..3] (dead after main loop; barrier before w3's writes
// makes it race-free) -> LDS 33KB, LDS allows 4 blocks/CU.
// R4 LESSON: no K double-buffer (spilled). setprio: R2 measured -12%.
// ---------------------------------------------------------------------------
#define NQ_   4                 // 16-row q sub-tiles per block
#define QB_   (NQ_ * 16)        // 64 queries per block
#define NQT_  (N_ / QB_)        // 32 q-tiles per bh

__global__ __launch_bounds__(256, 2)
void flash_mfma_kernel(const u16* __restrict__ qkv,
                       const u16* __restrict__ kpack,
                       const u16* __restrict__ vpack,
                       u16* __restrict__ attnb) {
    __shared__ __attribute__((aligned(16))) u16 Ps[4][QB_ * 64];  // per-wave P
    __shared__ float lex[QB_];
    float* Oex = (float*)&Ps[2][0];   // 16KB alias; Ps[2..3] dead at combine

    const int tid = threadIdx.x;
    const int w = tid >> 6, l = tid & 63;
    const int lq = l & 15, quad = l >> 4;
    const int sw = lq & 7;                 // P-row swizzle key

    // XCD-pinned remap: xcd = lin&7 owns bh {3x..3x+2}; NQT_ q-tiles per bh.
    const int lin  = blockIdx.x;
    const int slot = lin >> 3;                        // 0..95
    const int bh   = (lin & 7) * 3 + (slot / NQT_);   // 0..23
    const int qt   = slot & (NQT_ - 1);               // 64-query tile
    const int b = bh / H_, h = bh % H_;
    const size_t qbase = (size_t)b * N_ * QKVC + h * HD_;
    const size_t tbase = (size_t)bh * 32 * 4096;    // packed-tile base for bh

    // Q B-frags (all 4 waves: same QB_ queries)
    bf16x8 qb[NQ_][2];
#pragma unroll
    for (int nq = 0; nq < NQ_; ++nq)
#pragma unroll
        for (int ks = 0; ks < 2; ++ks)
            qb[nq][ks] = *(const bf16x8*)
                &qkv[qbase + (size_t)(qt * QB_ + nq * 16 + lq) * QKVC
                     + ks * 32 + quad * 8];

    float lsum[NQ_];
#pragma unroll
    for (int nq = 0; nq < NQ_; ++nq) lsum[nq] = 0.f;
    f32x4 oacc[4][NQ_];
    const f32x4 z4 = {0.f, 0.f, 0.f, 0.f};
#pragma unroll
    for (int mb = 0; mb < 4; ++mb)
#pragma unroll
        for (int nq = 0; nq < NQ_; ++nq) oacc[mb][nq] = z4;

    // preload K frags for first key tile (kt = w); fully coalesced 1KB loads
    bf16x8 ka[4][2];
#pragma unroll
    for (int kb = 0; kb < 4; ++kb)
#pragma unroll
        for (int ks = 0; ks < 2; ++ks)
            ka[kb][ks] = *(const bf16x8*)
                &kpack[tbase + (size_t)w * 4096 + ((kb * 2 + ks) * 64 + l) * 8];

    for (int kt2 = 0; kt2 < 8; ++kt2) {
        const int kt  = 4 * kt2 + w;
        const int ktn = (kt + 4) & 31;       // prefetch target (wrap harmless)
        const size_t vb = tbase + (size_t)kt * 4096;
        const size_t kb_n = tbase + (size_t)ktn * 4096;

        // V frags — issued early, consumed at PV below
        bf16x8 va[4][2];
#pragma unroll
        for (int mb = 0; mb < 4; ++mb)
#pragma unroll
            for (int ks = 0; ks < 2; ++ks)
                va[mb][ks] = *(const bf16x8*)
                    &vpack[vb + ((mb * 2 + ks) * 64 + l) * 8];

        // per-kb: S-MFMAs -> exp2 -> P-write (keeps sacc lifetime short)
#pragma unroll
        for (int kb = 0; kb < 4; ++kb) {
            f32x4 sacc[NQ_];
#pragma unroll
            for (int nq = 0; nq < NQ_; ++nq) sacc[nq] = z4;
            __builtin_amdgcn_s_setprio(1);
#pragma unroll
            for (int ks = 0; ks < 2; ++ks)
#pragma unroll
                for (int nq = 0; nq < NQ_; ++nq)
                    sacc[nq] = __builtin_amdgcn_mfma_f32_16x16x32_bf16(
                        ka[kb][ks], qb[nq][ks], sacc[nq], 0, 0, 0);
            __builtin_amdgcn_s_setprio(0);
#pragma unroll
            for (int nq = 0; nq < NQ_; ++nq) {
                float p[4];
#pragma unroll
                for (int r = 0; r < 4; ++r) p[r] = fexp2(sacc[nq][r] - SMAX);
                lsum[nq] += (p[0] + p[1]) + (p[2] + p[3]);
                uint2 pkv = { pk2(p[0], p[1]), pk2(p[2], p[3]) };
                *(uint2*)&Ps[w][(nq * 16 + lq) * 64
                                + (((kb * 2 + (quad >> 1)) ^ sw) * 8)
                                + (quad & 1) * 4] = pkv;
            }
        }

        // prefetch next K tile IN-PLACE (after all S-MFMAs consumed ka)
#pragma unroll
        for (int kb = 0; kb < 4; ++kb)
#pragma unroll
            for (int ks = 0; ks < 2; ++ks)
                ka[kb][ks] = *(const bf16x8*)
                    &kpack[kb_n + ((kb * 2 + ks) * 64 + l) * 8];

        // P B-frags (same-wave LDS RAW: DS-pipe ordered, no barrier)
        bf16x8 pb[2][NQ_];
#pragma unroll
        for (int ks = 0; ks < 2; ++ks)
#pragma unroll
            for (int nq = 0; nq < NQ_; ++nq)
                pb[ks][nq] = *(const bf16x8*)
                    &Ps[w][(nq * 16 + lq) * 64 + (((ks * 4 + quad) ^ sw) * 8)];

        // O^T += V^T.P^T
        __builtin_amdgcn_s_setprio(1);
#pragma unroll
        for (int mb = 0; mb < 4; ++mb)
#pragma unroll
            for (int ks = 0; ks < 2; ++ks)
#pragma unroll
                for (int nq = 0; nq < NQ_; ++nq)
                    oacc[mb][nq] = __builtin_amdgcn_mfma_f32_16x16x32_bf16(
                        va[mb][ks], pb[ks][nq], oacc[mb][nq], 0, 0, 0);
        __builtin_amdgcn_s_setprio(0);
    }

    // finish l: reduce over quad groups
#pragma unroll
    for (int nq = 0; nq < NQ_; ++nq) {
        lsum[nq] += __shfl_xor(lsum[nq], 16, 64);
        lsum[nq] += __shfl_xor(lsum[nq], 32, 64);
    }

    // All waves done with Ps[w] before Oex (= Ps[2..3]) is written.
    __syncthreads();

    // 4-way combine: w3 writes, w2/w1 add, w0 finalizes (barrier-separated).
    // Chunk addresses are disjoint across lanes (chunk = (mb*4+quad)^lq).
    if (w == 3) {
#pragma unroll
        for (int nq = 0; nq < NQ_; ++nq) {
#pragma unroll
            for (int mb = 0; mb < 4; ++mb) {
                const int chunk = (mb * 4 + quad) ^ lq;
                *(float4*)&Oex[(nq * 16 + lq) * 64 + chunk * 4] =
                    *(float4*)&oacc[mb][nq];
            }
            if (quad == 0) lex[nq * 16 + lq] = lsum[nq];
        }
    }
    __syncthreads();
    if (w == 2) {
#pragma unroll
        for (int nq = 0; nq < NQ_; ++nq) {
#pragma unroll
            for (int mb = 0; mb < 4; ++mb) {
                const int chunk = (mb * 4 + quad) ^ lq;
                float4* p = (float4*)&Oex[(nq * 16 + lq) * 64 + chunk * 4];
                float4 t = *p;
                t.x += oacc[mb][nq][0]; t.y += oacc[mb][nq][1];
                t.z += oacc[mb][nq][2]; t.w += oacc[mb][nq][3];
                *p = t;
            }
            if (quad == 0) lex[nq * 16 + lq] += lsum[nq];
        }
    }
    __syncthreads();
    if (w == 1) {
#pragma unroll
        for (int nq = 0; nq < NQ_; ++nq) {
#pragma unroll
            for (int mb = 0; mb < 4; ++mb) {
                const int chunk = (mb * 4 + quad) ^ lq;
                float4* p = (float4*)&Oex[(nq * 16 + lq) * 64 + chunk * 4];
                float4 t = *p;
                t.x += oacc[mb][nq][0]; t.y += oacc[mb][nq][1];
                t.z += oacc[mb][nq][2]; t.w += oacc[mb][nq][3];
                *p = t;
            }
            if (quad == 0) lex[nq * 16 + lq] += lsum[nq];
        }
    }
    __syncthreads();
    if (w == 0) {
#pragma unroll
        for (int nq = 0; nq < NQ_; ++nq) {
            const int qrow = nq * 16 + lq;
            const float inv = 1.f / (lsum[nq] + lex[qrow]);
#pragma unroll
            for (int mb = 0; mb < 4; ++mb) {
                const int chunk = (mb * 4 + quad) ^ lq;
                const float4 oe = *(const float4*)&Oex[qrow * 64 + chunk * 4];
                const float o0 = (oacc[mb][nq][0] + oe.x) * inv;
                const float o1 = (oacc[mb][nq][1] + oe.y) * inv;
                const float o2 = (oacc[mb][nq][2] + oe.z) * inv;
                const float o3 = (oacc[mb][nq][3] + oe.w) * inv;
                uint2 ov = { pk2(o0, o1), pk2(o2, o3) };
                *(uint2*)&Ps[0][qrow * 64
                                + (((mb * 2 + (quad >> 1)) ^ sw) * 8)
                                + (quad & 1) * 4] = ov;
            }
        }
        // coalesced 16B stores of QB_ q x 64 dv (Ps[0] staging, no Oex overlap)
#pragma unroll
        for (int pass = 0; pass < QB_ / 8; ++pass) {
            const int ql = pass * 8 + (l >> 3);          // 0..QB_-1
            const int c  = l & 7;                        // dv chunk
            const bf16x8 v = *(const bf16x8*)&Ps[0][ql * 64 + ((c ^ (ql & 7)) * 8)];
            const int query = qt * QB_ + ql;
            *(bf16x8*)&attnb[(size_t)(b * N_ + query) * C_ + h * HD_ + c * 8] = v;
        }
    }
}

// ---------------------------------------------------------------------------
extern "C" void kernel_launch(void* const* d_in, const int* in_sizes, int n_in,
                              void* d_out, int out_size, void* d_ws, size_t ws_size,
                              hipStream_t stream) {
    const float* x        = (const float*)d_in[0];
    const float* rope_cos = (const float*)d_in[1];
    const float* rope_sin = (const float*)d_in[2];
    const float* qkv_w    = (const float*)d_in[3];
    const float* qkv_b    = (const float*)d_in[4];
    const float* proj_w   = (const float*)d_in[5];
    const float* proj_b   = (const float*)d_in[6];
    const float* q_nw     = (const float*)d_in[7];
    const float* k_nw     = (const float*)d_in[8];
    float* out = (float*)d_out;

    // ws layout (bf16 buffers), ~42.5 MB. kpackb ALIASES xb: xb is dead after
    // gemm1; normvpack (writes kpackb) runs after gemm1 on the same stream.
    u16* xb    = (u16*)d_ws;                               // 4096x768
    u16* qwt   = xb    + (size_t)NROWS * C_;               // 2304x768 (W^T)
    u16* pwt   = qwt   + (size_t)QKVC * C_;                // 768x768  (W^T)
    u16* qkvb  = pwt   + (size_t)C_ * C_;                  // 4096x2304
    u16* vpackb= qkvb  + (size_t)NROWS * QKVC;             // 24x32x4096
    u16* attnb = vpackb+ (size_t)B_ * H_ * 32 * 4096;      // 4096x768
    u16* kpackb= xb;                                       // 24x32x4096 (alias)

    prep_kernel<<<dim3(576 + NROWS * C_ / 1024), 256, 0, stream>>>(
        x, xb, qkv_w, qwt, proj_w, pwt);

    gemm_tn_kernel<true, 128><<<dim3(QKVC / 128, NROWS / 128), 256, 0, stream>>>(
        xb, qwt, qkv_b, qkvb, NROWS, QKVC, C_);

    normvpack_kernel<<<dim3(768 + NROWS * H_ / 16), 256, 0, stream>>>(
        qkvb, kpackb, vpackb, rope_cos, rope_sin, q_nw, k_nw);

    flash_mfma_kernel<<<dim3(B_ * H_ * NQT_), 256, 0, stream>>>(
        qkvb, kpackb, vpackb, attnb);

    gemm_tn_kernel<false, 64><<<dim3(C_ / 64, NROWS / 128), 256, 0, stream>>>(
        attnb, pwt, proj_b, out, NROWS, C_, C_);
}

// Round 10
// 175.859 us; speedup vs baseline: 1.5096x; 1.0029x over previous
//
#include <hip/hip_runtime.h>
#include <math.h>

#define B_    2
#define N_    2048
#define C_    768
#define H_    12
#define HD_   64
#define NROWS (B_*N_)      // 4096
#define QKVC  (3*C_)       // 2304
#define EPSV  1e-6f
#define SCALE 0.125f       // 1/sqrt(HD)
#define LOG2E 1.44269504088896f
#define SMAX  12.0f        // static softmax max: logit*log2e <= 8*1.443+eps < 12

typedef unsigned short u16;
typedef short bf16x8 __attribute__((ext_vector_type(8)));   // 8 bf16 = 4 VGPRs
typedef float f32x4  __attribute__((ext_vector_type(4)));   // MFMA C/D

__device__ __forceinline__ float b2f(u16 u) {
    unsigned v = ((unsigned)u) << 16;
    return __builtin_bit_cast(float, v);
}
__device__ __forceinline__ u16 f2b(float f) {   // RNE
    unsigned u = __builtin_bit_cast(unsigned, f);
    u += 0x7fffu + ((u >> 16) & 1u);
    return (u16)(u >> 16);
}
__device__ __forceinline__ unsigned pk2(float a, float b) {
#if __has_builtin(__builtin_amdgcn_cvt_pk_bf16_f32)
    auto r = __builtin_amdgcn_cvt_pk_bf16_f32(a, b);
    return __builtin_bit_cast(unsigned, r);
#else
    return (unsigned)f2b(a) | ((unsigned)f2b(b) << 16);
#endif
}
__device__ __forceinline__ float fexp2(float x) {
#if __has_builtin(__builtin_amdgcn_exp2f)
    return __builtin_amdgcn_exp2f(x);
#else
    return exp2f(x);
#endif
}
// async global->LDS, 16B/lane; LDS dest = wave-uniform base + lane*16
__device__ __forceinline__ void gload_lds16(const void* g, void* l) {
    __builtin_amdgcn_global_load_lds(
        (const __attribute__((address_space(1))) unsigned int*)g,
        (__attribute__((address_space(3))) unsigned int*)l, 16, 0, 0);
}

// ---------------------------------------------------------------------------
// Fused prologue: [0,432) wtrans qkv_w, [432,576) wtrans proj_w,
// [576,3648) fp32->bf16 cvt of x. All independent; one launch instead of 3.
// Branch is block-uniform so the __syncthreads in wtrans is safe.
// ---------------------------------------------------------------------------
__device__ __forceinline__ void wtrans_body(const float* __restrict__ W,
                                            u16* __restrict__ Wt,
                                            int K, int N, int bx, int by,
                                            float (*T)[65]) {
    const int k0 = by * 64, n0 = bx * 64;
    const int t = threadIdx.x, r = t >> 6, c = t & 63;
#pragma unroll
    for (int p = 0; p < 16; ++p) {
        const int kl = p * 4 + r;
        T[kl][c] = W[(size_t)(k0 + kl) * N + n0 + c];
    }
    __syncthreads();
#pragma unroll
    for (int p = 0; p < 16; ++p) {
        const int nl = p * 4 + r;
        Wt[(size_t)(n0 + nl) * K + k0 + c] = f2b(T[c][nl]);
    }
}

__global__ __launch_bounds__(256)
void prep_kernel(const float* __restrict__ x, u16* __restrict__ xb,
                 const float* __restrict__ qkv_w, u16* __restrict__ qwt,
                 const float* __restrict__ proj_w, u16* __restrict__ pwt) {
    __shared__ float T[64][65];
    const int blk = blockIdx.x;
    if (blk < 432) {
        wtrans_body(qkv_w, qwt, C_, QKVC, blk % 36, blk / 36, T);
    } else if (blk < 576) {
        const int lin = blk - 432;
        wtrans_body(proj_w, pwt, C_, C_, lin % 12, lin / 12, T);
    } else {
        const int i = ((blk - 576) * 256 + threadIdx.x) * 4;
        const float4 v = *(const float4*)(x + i);
        uint2 o = { pk2(v.x, v.y), pk2(v.z, v.w) };
        *(uint2*)(xb + i) = o;
    }
}

// ---------------------------------------------------------------------------
// bf16 TN GEMM: C[M][N] = A[M][K] @ Bt[N][K]^T + bias
// 128xBN tile (BN=128 or 64), BK=32, 256 thr / 4 waves. LDS pitch 32 elem,
// 16B-chunk XOR swizzle (chunk ^= row&3) staged by inverting the swizzle on
// global addrs. XCD-chunked block remap (grid %8 == 0). BN=64 for the proj
// GEMM (N=768): 384 blocks vs 192.
// R6 LESSON: BK=64 regressed 5% (VGPR-capped occupancy; longer vmcnt(0)
// drain outweighed fewer barriers). Keep BK=32.
// ---------------------------------------------------------------------------
template <bool BF16OUT, int BN>
__global__ __launch_bounds__(256)
void gemm_tn_kernel(const u16* __restrict__ A, const u16* __restrict__ Bt,
                    const float* __restrict__ bias, void* __restrict__ Cout,
                    int M, int N, int K) {
    constexpr int NB = BN / 32;                 // nb frags per wave
    __shared__ __attribute__((aligned(16))) u16 As[128 * 32];
    __shared__ __attribute__((aligned(16))) u16 Bs[BN * 32];
    const int tid = threadIdx.x;
    const int w = tid >> 6, l = tid & 63;
    const int lq = l & 15, quad = l >> 4;

    // XCD-chunked remap
    const int gx  = gridDim.x;
    const int nwg = gx * gridDim.y;
    const int d   = blockIdx.x + gx * blockIdx.y;
    const int lin = (d & 7) * (nwg >> 3) + (d >> 3);
    const int mbase = (lin / gx) * 128, nbase = (lin % gx) * BN;

    f32x4 acc[4][NB];
    const f32x4 z4 = {0.f, 0.f, 0.f, 0.f};
#pragma unroll
    for (int mb = 0; mb < 4; ++mb)
#pragma unroll
        for (int nb = 0; nb < NB; ++nb) acc[mb][nb] = z4;

    const int srow = (l >> 2);
    const int sdc  = (l & 3) ^ ((l >> 2) & 3);

    for (int k0 = 0; k0 < K; k0 += 32) {
#pragma unroll
        for (int cc = 0; cc < 2; ++cc) {        // A: 8 chunks, 2 per wave
            const int c = 2 * w + cc;
            const int row = 16 * c + srow;
            gload_lds16(A + (size_t)(mbase + row) * K + k0 + sdc * 8, &As[c * 512]);
        }
#pragma unroll
        for (int cc = 0; cc < BN / 64; ++cc) {  // B: BN/16 chunks
            const int c = (BN / 64) * w + cc;
            const int row = 16 * c + srow;
            gload_lds16(Bt + (size_t)(nbase + row) * K + k0 + sdc * 8, &Bs[c * 512]);
        }
        __syncthreads();

        bf16x8 af[4], bfr[NB];
#pragma unroll
        for (int mb = 0; mb < 4; ++mb)
            af[mb] = *(const bf16x8*)
                &As[((w >> 1) * 64 + mb * 16 + lq) * 32 + ((quad ^ (lq & 3)) * 8)];
#pragma unroll
        for (int nb = 0; nb < NB; ++nb)
            bfr[nb] = *(const bf16x8*)
                &Bs[((w & 1) * (BN / 2) + nb * 16 + lq) * 32 + ((quad ^ (lq & 3)) * 8)];
#pragma unroll
        for (int mb = 0; mb < 4; ++mb)
#pragma unroll
            for (int nb = 0; nb < NB; ++nb)
                acc[mb][nb] = __builtin_amdgcn_mfma_f32_16x16x32_bf16(
                    af[mb], bfr[nb], acc[mb][nb], 0, 0, 0);
        __syncthreads();
    }

#pragma unroll
    for (int nb = 0; nb < NB; ++nb) {
        const int col = nbase + (w & 1) * (BN / 2) + nb * 16 + lq;
        const float bv = bias[col];
#pragma unroll
        for (int mb = 0; mb < 4; ++mb) {
#pragma unroll
            for (int r = 0; r < 4; ++r) {
                const int row = mbase + (w >> 1) * 64 + mb * 16 + quad * 4 + r;
                const float v = acc[mb][nb][r] + bv;
                if (BF16OUT) ((u16*)Cout)[(size_t)row * N + col] = f2b(v);
                else         ((float*)Cout)[(size_t)row * N + col] = v;
            }
        }
    }
}

// ---------------------------------------------------------------------------
// Fused normrope + vpack (independent regions of qkvb): [0,768) vpack
// (heavier blocks first), [768,3840) normrope. One launch instead of 2.
//
// normrope: RMSNorm + RoPE. 16 lanes per (row,h), ushort4 per lane.
// q (roped, *SCALE*LOG2E) -> back into qkv buffer.
// k (roped)               -> kpack, MFMA-A-fragment-packed tiles:
//   tile(bh,kt) base = (bh*32+kt)*4096 ; elem ((kb*2+ks)*64 + lane)*8 + j
//   where lane=(quad*16+m), K[key=kb*16+m][d=ks*32+quad*8+j].
// vpack: qkv V-region -> vpack, MFMA-A-fragment-packed V^T tiles.
// ---------------------------------------------------------------------------
__device__ __forceinline__ void normrope_body(
        u16* __restrict__ qkv, u16* __restrict__ kpack,
        const float* __restrict__ cosb, const float* __restrict__ sinb,
        const float* __restrict__ qw, const float* __restrict__ kw,
        int blk) {
    const int item = blk * 16 + (threadIdx.x >> 4); // (b*N+n)*H + h
    const int lq   = threadIdx.x & 15;
    const int h    = item % H_;
    const int row  = item / H_;        // b*N + n
    const int n    = row & (N_ - 1);
    const int b    = row >> 11;
    const size_t base = (size_t)row * QKVC + h * HD_ + lq * 4;

    const ushort4 q4 = *(const ushort4*)&qkv[base];
    const ushort4 k4 = *(const ushort4*)&qkv[base + C_];
    float qf[4], kf[4];
    qf[0] = b2f(q4.x); qf[1] = b2f(q4.y); qf[2] = b2f(q4.z); qf[3] = b2f(q4.w);
    kf[0] = b2f(k4.x); kf[1] = b2f(k4.y); kf[2] = b2f(k4.z); kf[3] = b2f(k4.w);

    float q2 = qf[0]*qf[0] + qf[1]*qf[1] + qf[2]*qf[2] + qf[3]*qf[3];
    float k2 = kf[0]*kf[0] + kf[1]*kf[1] + kf[2]*kf[2] + kf[3]*kf[3];
#pragma unroll
    for (int off = 8; off >= 1; off >>= 1) {
        q2 += __shfl_xor(q2, off, 64);
        k2 += __shfl_xor(k2, off, 64);
    }
    const float rq = rsqrtf(q2 * (1.f / 64.f) + EPSV);
    const float rk = rsqrtf(k2 * (1.f / 64.f) + EPSV);

    const float4 qwv = *(const float4*)&qw[lq * 4];
    const float4 kwv = *(const float4*)&kw[lq * 4];
    const float4 cv  = *(const float4*)&cosb[n * HD_ + lq * 4];
    const float4 sv  = *(const float4*)&sinb[n * HD_ + lq * 4];

    float qn[4], kn[4];
    qn[0] = qf[0]*rq*qwv.x; qn[1] = qf[1]*rq*qwv.y;
    qn[2] = qf[2]*rq*qwv.z; qn[3] = qf[3]*rq*qwv.w;
    kn[0] = kf[0]*rk*kwv.x; kn[1] = kf[1]*rk*kwv.y;
    kn[2] = kf[2]*rk*kwv.z; kn[3] = kf[3]*rk*kwv.w;

    const float sgn = (lq < 8) ? -1.f : 1.f;   // partner lane = lq^8 (d +/- 32)
    float qo[4], ko[4];
    const float cc[4] = {cv.x, cv.y, cv.z, cv.w};
    const float ss[4] = {sv.x, sv.y, sv.z, sv.w};
#pragma unroll
    for (int j = 0; j < 4; ++j) {
        const float qp = __shfl_xor(qn[j], 8, 64);
        const float kp = __shfl_xor(kn[j], 8, 64);
        qo[j] = (qn[j] * cc[j] + sgn * qp * ss[j]) * (SCALE * LOG2E);
        ko[j] =  kn[j] * cc[j] + sgn * kp * ss[j];
    }
    uint2 qout = { pk2(qo[0], qo[1]), pk2(qo[2], qo[3]) };
    uint2 kout = { pk2(ko[0], ko[1]), pk2(ko[2], ko[3]) };
    *(uint2*)&qkv[base] = qout;

    // k -> fragment-packed tile
    const int kt = n >> 6, kr = n & 63;
    const int kb = kr >> 4, m = kr & 15;
    const int ks = lq >> 3, quad = (lq >> 1) & 3, jj = (lq & 1) * 4;
    const size_t off = ((size_t)(b * H_ + h) * 32 + kt) * 4096
                     + (size_t)((kb * 2 + ks) * 64 + quad * 16 + m) * 8 + jj;
    *(uint2*)&kpack[off] = kout;
}

__device__ __forceinline__ void vpack_body(
        const u16* __restrict__ qkv, u16* __restrict__ vpack,
        int kt, int bh, u16 (*Tv)[72]) {
    const int b = bh / H_, h = bh % H_;
    const int t = threadIdx.x;
    {
        const int r = t >> 2, seg = t & 3;   // row=key, 16 u16 per thread
        const u16* src = &qkv[(size_t)(b * N_ + kt * 64 + r) * QKVC
                              + 2 * C_ + h * HD_ + seg * 16];
        const uint4 v0 = *(const uint4*)src;
        const uint4 v1 = *(const uint4*)(src + 8);
        *(uint4*)&Tv[r][seg * 16]     = v0;
        *(uint4*)&Tv[r][seg * 16 + 8] = v1;
    }
    __syncthreads();
    u16 tmp[16];
#pragma unroll
    for (int g2 = 0; g2 < 2; ++g2) {
        const int g = t * 2 + g2;            // j-group 0..511
        const int mbks = g >> 6;             // (mb*2+ks)
        const int l  = g & 63;
        const int mb = mbks >> 1, ks = mbks & 1;
        const int m  = l & 15,  quad = l >> 4;
#pragma unroll
        for (int j = 0; j < 8; ++j)
            tmp[g2 * 8 + j] = Tv[ks * 32 + quad * 8 + j][mb * 16 + m];
    }
    u16* dst = &vpack[((size_t)bh * 32 + kt) * 4096 + t * 16];
    *(uint4*)dst       = *(const uint4*)&tmp[0];
    *(uint4*)(dst + 8) = *(const uint4*)&tmp[8];
}

__global__ __launch_bounds__(256)
void normvpack_kernel(u16* __restrict__ qkv, u16* __restrict__ kpack,
                      u16* __restrict__ vpack,
                      const float* __restrict__ cosb,
                      const float* __restrict__ sinb,
                      const float* __restrict__ qw,
                      const float* __restrict__ kw) {
    __shared__ u16 Tv[64][72];
    const int blk = blockIdx.x;
    if (blk < 768) {
        vpack_body(qkv, vpack, blk & 31, blk >> 5, Tv);
    } else {
        normrope_body(qkv, kpack, cosb, sinb, qw, kw, blk - 768);
    }
}

// ---------------------------------------------------------------------------
// MFMA flash attention. Block = 2 waves over the SAME 32 queries (nq=2);
// wave w handles keys kt = (2*kt2 + w + 2*qt) & 31 -- R10: qt-STAGGERED ring
// start. Rationale: eliminated theories for the ~45us plateau: occupancy x2
// (R1 null), prefetch placement (R7 null), S-batching (R7 null), L2 BW (R9:
// half traffic -> SLOWER). Remaining suspect: L2 hot-line congestion -- all
// 64 qt-blocks of a bh previously walked the same 32 K/V tiles in lockstep
// from the same start, queueing dozens of waves on each L2 line. The stagger
// spreads blocks across 16 ring positions at zero instruction cost; partials
// are order-independent (static-max softmax, additive).
// R4/R8 LESSONS: no K double-buffer, no tight launch_bounds (both spill).
// setprio: R2 measured -12%.
// ---------------------------------------------------------------------------
#define NQ_   2                 // 16-row q sub-tiles per block
#define QB_   (NQ_ * 16)        // 32 queries per block
#define NQT_  (N_ / QB_)        // 64 q-tiles per bh

__global__ __launch_bounds__(128, 3)
void flash_mfma_kernel(const u16* __restrict__ qkv,
                       const u16* __restrict__ kpack,
                       const u16* __restrict__ vpack,
                       u16* __restrict__ attnb) {
    __shared__ __attribute__((aligned(16))) u16 Ps[2][QB_ * 64];  // per-wave P
    __shared__ __attribute__((aligned(16))) float Oex[QB_ * 64];  // exchange
    __shared__ float lex[QB_];

    const int tid = threadIdx.x;
    const int w = tid >> 6, l = tid & 63;
    const int lq = l & 15, quad = l >> 4;
    const int sw = lq & 7;                 // P-row swizzle key

    // XCD-pinned remap: xcd = lin&7 owns bh {3x..3x+2}; NQT_ q-tiles per bh.
    const int lin  = blockIdx.x;
    const int slot = lin >> 3;                        // 0..191
    const int bh   = (lin & 7) * 3 + (slot / NQT_);   // 0..23
    const int qt   = slot & (NQT_ - 1);               // 32-query tile
    const int b = bh / H_, h = bh % H_;
    const size_t qbase = (size_t)b * N_ * QKVC + h * HD_;
    const size_t tbase = (size_t)bh * 32 * 4096;    // packed-tile base for bh
    const int ktoff = (qt * 2) & 31;                // per-block ring stagger

    // Q B-frags (both waves: same QB_ queries)
    bf16x8 qb[NQ_][2];
#pragma unroll
    for (int nq = 0; nq < NQ_; ++nq)
#pragma unroll
        for (int ks = 0; ks < 2; ++ks)
            qb[nq][ks] = *(const bf16x8*)
                &qkv[qbase + (size_t)(qt * QB_ + nq * 16 + lq) * QKVC
                     + ks * 32 + quad * 8];

    float lsum[NQ_];
#pragma unroll
    for (int nq = 0; nq < NQ_; ++nq) lsum[nq] = 0.f;
    f32x4 oacc[4][NQ_];
    const f32x4 z4 = {0.f, 0.f, 0.f, 0.f};
#pragma unroll
    for (int mb = 0; mb < 4; ++mb)
#pragma unroll
        for (int nq = 0; nq < NQ_; ++nq) oacc[mb][nq] = z4;

    // preload K frags for first key tile (kt = (w+ktoff)&31)
    bf16x8 ka[4][2];
#pragma unroll
    for (int kb = 0; kb < 4; ++kb)
#pragma unroll
        for (int ks = 0; ks < 2; ++ks)
            ka[kb][ks] = *(const bf16x8*)
                &kpack[tbase + (size_t)((w + ktoff) & 31) * 4096
                       + ((kb * 2 + ks) * 64 + l) * 8];

    for (int kt2 = 0; kt2 < 16; ++kt2) {
        const int kt  = (2 * kt2 + w + ktoff) & 31;
        const int ktn = (kt + 2) & 31;       // prefetch target (wrap harmless)
        const size_t vb = tbase + (size_t)kt * 4096;
        const size_t kb_n = tbase + (size_t)ktn * 4096;

        // V frags — issued early, consumed at PV below
        bf16x8 va[4][2];
#pragma unroll
        for (int mb = 0; mb < 4; ++mb)
#pragma unroll
            for (int ks = 0; ks < 2; ++ks)
                va[mb][ks] = *(const bf16x8*)
                    &vpack[vb + ((mb * 2 + ks) * 64 + l) * 8];

        // per-kb: S-MFMAs -> exp2 -> P-write (keeps sacc lifetime short)
#pragma unroll
        for (int kb = 0; kb < 4; ++kb) {
            f32x4 sacc[NQ_];
#pragma unroll
            for (int nq = 0; nq < NQ_; ++nq) sacc[nq] = z4;
            __builtin_amdgcn_s_setprio(1);
#pragma unroll
            for (int ks = 0; ks < 2; ++ks)
#pragma unroll
                for (int nq = 0; nq < NQ_; ++nq)
                    sacc[nq] = __builtin_amdgcn_mfma_f32_16x16x32_bf16(
                        ka[kb][ks], qb[nq][ks], sacc[nq], 0, 0, 0);
            __builtin_amdgcn_s_setprio(0);
#pragma unroll
            for (int nq = 0; nq < NQ_; ++nq) {
                float p[4];
#pragma unroll
                for (int r = 0; r < 4; ++r) p[r] = fexp2(sacc[nq][r] - SMAX);
                lsum[nq] += (p[0] + p[1]) + (p[2] + p[3]);
                uint2 pkv = { pk2(p[0], p[1]), pk2(p[2], p[3]) };
                *(uint2*)&Ps[w][(nq * 16 + lq) * 64
                                + (((kb * 2 + (quad >> 1)) ^ sw) * 8)
                                + (quad & 1) * 4] = pkv;
            }
        }

        // prefetch next K tile IN-PLACE (after all S-MFMAs consumed ka)
#pragma unroll
        for (int kb = 0; kb < 4; ++kb)
#pragma unroll
            for (int ks = 0; ks < 2; ++ks)
                ka[kb][ks] = *(const bf16x8*)
                    &kpack[kb_n + ((kb * 2 + ks) * 64 + l) * 8];

        // P B-frags (same-wave LDS RAW: DS-pipe ordered, no barrier)
        bf16x8 pb[2][NQ_];
#pragma unroll
        for (int ks = 0; ks < 2; ++ks)
#pragma unroll
            for (int nq = 0; nq < NQ_; ++nq)
                pb[ks][nq] = *(const bf16x8*)
                    &Ps[w][(nq * 16 + lq) * 64 + (((ks * 4 + quad) ^ sw) * 8)];

        // O^T += V^T.P^T
        __builtin_amdgcn_s_setprio(1);
#pragma unroll
        for (int mb = 0; mb < 4; ++mb)
#pragma unroll
            for (int ks = 0; ks < 2; ++ks)
#pragma unroll
                for (int nq = 0; nq < NQ_; ++nq)
                    oacc[mb][nq] = __builtin_amdgcn_mfma_f32_16x16x32_bf16(
                        va[mb][ks], pb[ks][nq], oacc[mb][nq], 0, 0, 0);
        __builtin_amdgcn_s_setprio(0);
    }

    // finish l: reduce over quad groups
#pragma unroll
    for (int nq = 0; nq < NQ_; ++nq) {
        lsum[nq] += __shfl_xor(lsum[nq], 16, 64);
        lsum[nq] += __shfl_xor(lsum[nq], 32, 64);
    }

    // combine key-halves: wave1 -> LDS, barrier, wave0 finalizes
    if (w == 1) {
#pragma unroll
        for (int nq = 0; nq < NQ_; ++nq) {
#pragma unroll
            for (int mb = 0; mb < 4; ++mb) {
                const int chunk = (mb * 4 + quad) ^ lq;   // float4-chunk swizzle
                *(float4*)&Oex[(nq * 16 + lq) * 64 + chunk * 4] =
                    *(float4*)&oacc[mb][nq];
            }
            if (quad == 0) lex[nq * 16 + lq] = lsum[nq];
        }
    }
    __syncthreads();
    if (w == 0) {
#pragma unroll
        for (int nq = 0; nq < NQ_; ++nq) {
            const int qrow = nq * 16 + lq;
            const float inv = 1.f / (lsum[nq] + lex[qrow]);
#pragma unroll
            for (int mb = 0; mb < 4; ++mb) {
                const int chunk = (mb * 4 + quad) ^ lq;
                const float4 oe = *(const float4*)&Oex[qrow * 64 + chunk * 4];
                const float o0 = (oacc[mb][nq][0] + oe.x) * inv;
                const float o1 = (oacc[mb][nq][1] + oe.y) * inv;
                const float o2 = (oacc[mb][nq][2] + oe.z) * inv;
                const float o3 = (oacc[mb][nq][3] + oe.w) * inv;
                uint2 ov = { pk2(o0, o1), pk2(o2, o3) };
                *(uint2*)&Ps[0][qrow * 64
                                + (((mb * 2 + (quad >> 1)) ^ sw) * 8)
                                + (quad & 1) * 4] = ov;
            }
        }
        // coalesced 16B stores of QB_ q x 64 dv
#pragma unroll
        for (int pass = 0; pass < QB_ / 8; ++pass) {
            const int ql = pass * 8 + (l >> 3);          // 0..QB_-1
            const int c  = l & 7;                        // dv chunk
            const bf16x8 v = *(const bf16x8*)&Ps[0][ql * 64 + ((c ^ (ql & 7)) * 8)];
            const int query = qt * QB_ + ql;
            *(bf16x8*)&attnb[(size_t)(b * N_ + query) * C_ + h * HD_ + c * 8] = v;
        }
    }
}

// ---------------------------------------------------------------------------
extern "C" void kernel_launch(void* const* d_in, const int* in_sizes, int n_in,
                              void* d_out, int out_size, void* d_ws, size_t ws_size,
                              hipStream_t stream) {
    const float* x        = (const float*)d_in[0];
    const float* rope_cos = (const float*)d_in[1];
    const float* rope_sin = (const float*)d_in[2];
    const float* qkv_w    = (const float*)d_in[3];
    const float* qkv_b    = (const float*)d_in[4];
    const float* proj_w   = (const float*)d_in[5];
    const float* proj_b   = (const float*)d_in[6];
    const float* q_nw     = (const float*)d_in[7];
    const float* k_nw     = (const float*)d_in[8];
    float* out = (float*)d_out;

    // ws layout (bf16 buffers), ~42.5 MB. kpackb ALIASES xb: xb is dead after
    // gemm1; normvpack (writes kpackb) runs after gemm1 on the same stream.
    u16* xb    = (u16*)d_ws;                               // 4096x768
    u16* qwt   = xb    + (size_t)NROWS * C_;               // 2304x768 (W^T)
    u16* pwt   = qwt   + (size_t)QKVC * C_;                // 768x768  (W^T)
    u16* qkvb  = pwt   + (size_t)C_ * C_;                  // 4096x2304
    u16* vpackb= qkvb  + (size_t)NROWS * QKVC;             // 24x32x4096
    u16* attnb = vpackb+ (size_t)B_ * H_ * 32 * 4096;      // 4096x768
    u16* kpackb= xb;                                       // 24x32x4096 (alias)

    prep_kernel<<<dim3(576 + NROWS * C_ / 1024), 256, 0, stream>>>(
        x, xb, qkv_w, qwt, proj_w, pwt);

    gemm_tn_kernel<true, 128><<<dim3(QKVC / 128, NROWS / 128), 256, 0, stream>>>(
        xb, qwt, qkv_b, qkvb, NROWS, QKVC, C_);

    normvpack_kernel<<<dim3(768 + NROWS * H_ / 16), 256, 0, stream>>>(
        qkvb, kpackb, vpackb, rope_cos, rope_sin, q_nw, k_nw);

    flash_mfma_kernel<<<dim3(B_ * H_ * NQT_), 128, 0, stream>>>(
        qkvb, kpackb, vpackb, attnb);

    gemm_tn_kernel<false, 64><<<dim3(C_ / 64, NROWS / 128), 256, 0, stream>>>(
        attnb, pwt, proj_b, out, NROWS, C_, C_);
}

// Round 11
// 171.774 us; speedup vs baseline: 1.5455x; 1.0238x over previous
//
#include <hip/hip_runtime.h>
#include <math.h>

#define B_    2
#define N_    2048
#define C_    768
#define H_    12
#define HD_   64
#define NROWS (B_*N_)      // 4096
#define QKVC  (3*C_)       // 2304
#define EPSV  1e-6f
#define SCALE 0.125f       // 1/sqrt(HD)
#define LOG2E 1.44269504088896f
#define SMAX  12.0f        // static softmax max: logit*log2e <= 8*1.443+eps < 12

typedef unsigned short u16;
typedef short bf16x8 __attribute__((ext_vector_type(8)));   // 8 bf16 = 4 VGPRs
typedef float f32x4  __attribute__((ext_vector_type(4)));   // MFMA C/D

__device__ __forceinline__ float b2f(u16 u) {
    unsigned v = ((unsigned)u) << 16;
    return __builtin_bit_cast(float, v);
}
__device__ __forceinline__ u16 f2b(float f) {   // RNE
    unsigned u = __builtin_bit_cast(unsigned, f);
    u += 0x7fffu + ((u >> 16) & 1u);
    return (u16)(u >> 16);
}
__device__ __forceinline__ unsigned pk2(float a, float b) {
#if __has_builtin(__builtin_amdgcn_cvt_pk_bf16_f32)
    auto r = __builtin_amdgcn_cvt_pk_bf16_f32(a, b);
    return __builtin_bit_cast(unsigned, r);
#else
    return (unsigned)f2b(a) | ((unsigned)f2b(b) << 16);
#endif
}
__device__ __forceinline__ float fexp2(float x) {
#if __has_builtin(__builtin_amdgcn_exp2f)
    return __builtin_amdgcn_exp2f(x);
#else
    return exp2f(x);
#endif
}
// async global->LDS, 16B/lane; LDS dest = wave-uniform base + lane*16
__device__ __forceinline__ void gload_lds16(const void* g, void* l) {
    __builtin_amdgcn_global_load_lds(
        (const __attribute__((address_space(1))) unsigned int*)g,
        (__attribute__((address_space(3))) unsigned int*)l, 16, 0, 0);
}

// ---------------------------------------------------------------------------
// Fused prologue: [0,432) wtrans qkv_w, [432,576) wtrans proj_w,
// [576,3648) fp32->bf16 cvt of x. All independent; one launch instead of 3.
// Branch is block-uniform so the __syncthreads in wtrans is safe.
// ---------------------------------------------------------------------------
__device__ __forceinline__ void wtrans_body(const float* __restrict__ W,
                                            u16* __restrict__ Wt,
                                            int K, int N, int bx, int by,
                                            float (*T)[65]) {
    const int k0 = by * 64, n0 = bx * 64;
    const int t = threadIdx.x, r = t >> 6, c = t & 63;
#pragma unroll
    for (int p = 0; p < 16; ++p) {
        const int kl = p * 4 + r;
        T[kl][c] = W[(size_t)(k0 + kl) * N + n0 + c];
    }
    __syncthreads();
#pragma unroll
    for (int p = 0; p < 16; ++p) {
        const int nl = p * 4 + r;
        Wt[(size_t)(n0 + nl) * K + k0 + c] = f2b(T[c][nl]);
    }
}

__global__ __launch_bounds__(256)
void prep_kernel(const float* __restrict__ x, u16* __restrict__ xb,
                 const float* __restrict__ qkv_w, u16* __restrict__ qwt,
                 const float* __restrict__ proj_w, u16* __restrict__ pwt) {
    __shared__ float T[64][65];
    const int blk = blockIdx.x;
    if (blk < 432) {
        wtrans_body(qkv_w, qwt, C_, QKVC, blk % 36, blk / 36, T);
    } else if (blk < 576) {
        const int lin = blk - 432;
        wtrans_body(proj_w, pwt, C_, C_, lin % 12, lin / 12, T);
    } else {
        const int i = ((blk - 576) * 256 + threadIdx.x) * 4;
        const float4 v = *(const float4*)(x + i);
        uint2 o = { pk2(v.x, v.y), pk2(v.z, v.w) };
        *(uint2*)(xb + i) = o;
    }
}

// ---------------------------------------------------------------------------
// bf16 TN GEMM: C[M][N] = A[M][K] @ Bt[N][K]^T + bias
// 128xBN tile (BN=128 or 64), BK=32, 256 thr / 4 waves.
// R11: explicit LDS DOUBLE-BUFFER, stage-before-compute, ONE barrier per
// K-step (T3 "minimum 2-phase" recipe). Old structure was stage ->
// syncthreads (immediate vmcnt(0) drain: zero compute cover, full L2
// latency exposed every iter) -> compute -> syncthreads. New: STAGE(next)
// issued at top, then ds_read+MFMA of current (~300cy of cover), then a
// single barrier whose vmcnt(0) drain sees mostly-landed loads.
// NOT R6's failed BK=64: per-drain staged bytes unchanged; only overlap
// and barrier count improve. LDS 33KB -- grid (576/384 blocks, ~2/CU)
// limits residency, not LDS.
// LDS pitch 32 elem, 16B-chunk XOR swizzle (chunk ^= row&3) staged by
// inverting the swizzle on global addrs. XCD-chunked block remap
// (grid %8 == 0). BN=64 for the proj GEMM (N=768): 384 blocks vs 192.
// ---------------------------------------------------------------------------
template <bool BF16OUT, int BN>
__global__ __launch_bounds__(256)
void gemm_tn_kernel(const u16* __restrict__ A, const u16* __restrict__ Bt,
                    const float* __restrict__ bias, void* __restrict__ Cout,
                    int M, int N, int K) {
    constexpr int NB = BN / 32;                 // nb frags per wave
    __shared__ __attribute__((aligned(16))) u16 As[2][128 * 32];
    __shared__ __attribute__((aligned(16))) u16 Bs[2][BN * 32];
    const int tid = threadIdx.x;
    const int w = tid >> 6, l = tid & 63;
    const int lq = l & 15, quad = l >> 4;

    // XCD-chunked remap
    const int gx  = gridDim.x;
    const int nwg = gx * gridDim.y;
    const int d   = blockIdx.x + gx * blockIdx.y;
    const int lin = (d & 7) * (nwg >> 3) + (d >> 3);
    const int mbase = (lin / gx) * 128, nbase = (lin % gx) * BN;

    f32x4 acc[4][NB];
    const f32x4 z4 = {0.f, 0.f, 0.f, 0.f};
#pragma unroll
    for (int mb = 0; mb < 4; ++mb)
#pragma unroll
        for (int nb = 0; nb < NB; ++nb) acc[mb][nb] = z4;

    const int srow = (l >> 2);
    const int sdc  = (l & 3) ^ ((l >> 2) & 3);

    auto stage = [&](int bi, int k0) {
#pragma unroll
        for (int cc = 0; cc < 2; ++cc) {        // A: 8 chunks, 2 per wave
            const int c = 2 * w + cc;
            const int row = 16 * c + srow;
            gload_lds16(A + (size_t)(mbase + row) * K + k0 + sdc * 8,
                        &As[bi][c * 512]);
        }
#pragma unroll
        for (int cc = 0; cc < BN / 64; ++cc) {  // B: BN/16 chunks
            const int c = (BN / 64) * w + cc;
            const int row = 16 * c + srow;
            gload_lds16(Bt + (size_t)(nbase + row) * K + k0 + sdc * 8,
                        &Bs[bi][c * 512]);
        }
    };

    stage(0, 0);
    __syncthreads();          // compiler drains vmcnt(0) before s_barrier

    int cur = 0;
    for (int k0 = 0; k0 < K; k0 += 32) {
        if (k0 + 32 < K) stage(cur ^ 1, k0 + 32);   // overlap with compute

        bf16x8 af[4], bfr[NB];
#pragma unroll
        for (int mb = 0; mb < 4; ++mb)
            af[mb] = *(const bf16x8*)
                &As[cur][((w >> 1) * 64 + mb * 16 + lq) * 32 + ((quad ^ (lq & 3)) * 8)];
#pragma unroll
        for (int nb = 0; nb < NB; ++nb)
            bfr[nb] = *(const bf16x8*)
                &Bs[cur][((w & 1) * (BN / 2) + nb * 16 + lq) * 32 + ((quad ^ (lq & 3)) * 8)];
#pragma unroll
        for (int mb = 0; mb < 4; ++mb)
#pragma unroll
            for (int nb = 0; nb < NB; ++nb)
                acc[mb][nb] = __builtin_amdgcn_mfma_f32_16x16x32_bf16(
                    af[mb], bfr[nb], acc[mb][nb], 0, 0, 0);

        __syncthreads();      // single barrier: next-tile loads mostly landed
        cur ^= 1;
    }

#pragma unroll
    for (int nb = 0; nb < NB; ++nb) {
        const int col = nbase + (w & 1) * (BN / 2) + nb * 16 + lq;
        const float bv = bias[col];
#pragma unroll
        for (int mb = 0; mb < 4; ++mb) {
#pragma unroll
            for (int r = 0; r < 4; ++r) {
                const int row = mbase + (w >> 1) * 64 + mb * 16 + quad * 4 + r;
                const float v = acc[mb][nb][r] + bv;
                if (BF16OUT) ((u16*)Cout)[(size_t)row * N + col] = f2b(v);
                else         ((float*)Cout)[(size_t)row * N + col] = v;
            }
        }
    }
}

// ---------------------------------------------------------------------------
// Fused normrope + vpack (independent regions of qkvb): [0,768) vpack
// (heavier blocks first), [768,3840) normrope. One launch instead of 2.
//
// normrope: RMSNorm + RoPE. 16 lanes per (row,h), ushort4 per lane.
// q (roped, *SCALE*LOG2E) -> back into qkv buffer.
// k (roped)               -> kpack, MFMA-A-fragment-packed tiles:
//   tile(bh,kt) base = (bh*32+kt)*4096 ; elem ((kb*2+ks)*64 + lane)*8 + j
//   where lane=(quad*16+m), K[key=kb*16+m][d=ks*32+quad*8+j].
// vpack: qkv V-region -> vpack, MFMA-A-fragment-packed V^T tiles.
// ---------------------------------------------------------------------------
__device__ __forceinline__ void normrope_body(
        u16* __restrict__ qkv, u16* __restrict__ kpack,
        const float* __restrict__ cosb, const float* __restrict__ sinb,
        const float* __restrict__ qw, const float* __restrict__ kw,
        int blk) {
    const int item = blk * 16 + (threadIdx.x >> 4); // (b*N+n)*H + h
    const int lq   = threadIdx.x & 15;
    const int h    = item % H_;
    const int row  = item / H_;        // b*N + n
    const int n    = row & (N_ - 1);
    const int b    = row >> 11;
    const size_t base = (size_t)row * QKVC + h * HD_ + lq * 4;

    const ushort4 q4 = *(const ushort4*)&qkv[base];
    const ushort4 k4 = *(const ushort4*)&qkv[base + C_];
    float qf[4], kf[4];
    qf[0] = b2f(q4.x); qf[1] = b2f(q4.y); qf[2] = b2f(q4.z); qf[3] = b2f(q4.w);
    kf[0] = b2f(k4.x); kf[1] = b2f(k4.y); kf[2] = b2f(k4.z); kf[3] = b2f(k4.w);

    float q2 = qf[0]*qf[0] + qf[1]*qf[1] + qf[2]*qf[2] + qf[3]*qf[3];
    float k2 = kf[0]*kf[0] + kf[1]*kf[1] + kf[2]*kf[2] + kf[3]*kf[3];
#pragma unroll
    for (int off = 8; off >= 1; off >>= 1) {
        q2 += __shfl_xor(q2, off, 64);
        k2 += __shfl_xor(k2, off, 64);
    }
    const float rq = rsqrtf(q2 * (1.f / 64.f) + EPSV);
    const float rk = rsqrtf(k2 * (1.f / 64.f) + EPSV);

    const float4 qwv = *(const float4*)&qw[lq * 4];
    const float4 kwv = *(const float4*)&kw[lq * 4];
    const float4 cv  = *(const float4*)&cosb[n * HD_ + lq * 4];
    const float4 sv  = *(const float4*)&sinb[n * HD_ + lq * 4];

    float qn[4], kn[4];
    qn[0] = qf[0]*rq*qwv.x; qn[1] = qf[1]*rq*qwv.y;
    qn[2] = qf[2]*rq*qwv.z; qn[3] = qf[3]*rq*qwv.w;
    kn[0] = kf[0]*rk*kwv.x; kn[1] = kf[1]*rk*kwv.y;
    kn[2] = kf[2]*rk*kwv.z; kn[3] = kf[3]*rk*kwv.w;

    const float sgn = (lq < 8) ? -1.f : 1.f;   // partner lane = lq^8 (d +/- 32)
    float qo[4], ko[4];
    const float cc[4] = {cv.x, cv.y, cv.z, cv.w};
    const float ss[4] = {sv.x, sv.y, sv.z, sv.w};
#pragma unroll
    for (int j = 0; j < 4; ++j) {
        const float qp = __shfl_xor(qn[j], 8, 64);
        const float kp = __shfl_xor(kn[j], 8, 64);
        qo[j] = (qn[j] * cc[j] + sgn * qp * ss[j]) * (SCALE * LOG2E);
        ko[j] =  kn[j] * cc[j] + sgn * kp * ss[j];
    }
    uint2 qout = { pk2(qo[0], qo[1]), pk2(qo[2], qo[3]) };
    uint2 kout = { pk2(ko[0], ko[1]), pk2(ko[2], ko[3]) };
    *(uint2*)&qkv[base] = qout;

    // k -> fragment-packed tile
    const int kt = n >> 6, kr = n & 63;
    const int kb = kr >> 4, m = kr & 15;
    const int ks = lq >> 3, quad = (lq >> 1) & 3, jj = (lq & 1) * 4;
    const size_t off = ((size_t)(b * H_ + h) * 32 + kt) * 4096
                     + (size_t)((kb * 2 + ks) * 64 + quad * 16 + m) * 8 + jj;
    *(uint2*)&kpack[off] = kout;
}

__device__ __forceinline__ void vpack_body(
        const u16* __restrict__ qkv, u16* __restrict__ vpack,
        int kt, int bh, u16 (*Tv)[72]) {
    const int b = bh / H_, h = bh % H_;
    const int t = threadIdx.x;
    {
        const int r = t >> 2, seg = t & 3;   // row=key, 16 u16 per thread
        const u16* src = &qkv[(size_t)(b * N_ + kt * 64 + r) * QKVC
                              + 2 * C_ + h * HD_ + seg * 16];
        const uint4 v0 = *(const uint4*)src;
        const uint4 v1 = *(const uint4*)(src + 8);
        *(uint4*)&Tv[r][seg * 16]     = v0;
        *(uint4*)&Tv[r][seg * 16 + 8] = v1;
    }
    __syncthreads();
    u16 tmp[16];
#pragma unroll
    for (int g2 = 0; g2 < 2; ++g2) {
        const int g = t * 2 + g2;            // j-group 0..511
        const int mbks = g >> 6;             // (mb*2+ks)
        const int l  = g & 63;
        const int mb = mbks >> 1, ks = mbks & 1;
        const int m  = l & 15,  quad = l >> 4;
#pragma unroll
        for (int j = 0; j < 8; ++j)
            tmp[g2 * 8 + j] = Tv[ks * 32 + quad * 8 + j][mb * 16 + m];
    }
    u16* dst = &vpack[((size_t)bh * 32 + kt) * 4096 + t * 16];
    *(uint4*)dst       = *(const uint4*)&tmp[0];
    *(uint4*)(dst + 8) = *(const uint4*)&tmp[8];
}

__global__ __launch_bounds__(256)
void normvpack_kernel(u16* __restrict__ qkv, u16* __restrict__ kpack,
                      u16* __restrict__ vpack,
                      const float* __restrict__ cosb,
                      const float* __restrict__ sinb,
                      const float* __restrict__ qw,
                      const float* __restrict__ kw) {
    __shared__ u16 Tv[64][72];
    const int blk = blockIdx.x;
    if (blk < 768) {
        vpack_body(qkv, vpack, blk & 31, blk >> 5, Tv);
    } else {
        normrope_body(qkv, kpack, cosb, sinb, qw, kw, blk - 768);
    }
}

// ---------------------------------------------------------------------------
// MFMA flash attention. Block = 2 waves over the SAME 32 queries (nq=2);
// wave w handles keys kt = 2*kt2+w. R5-exact structure (best measured:
// flash 45.0us). Flash theory scoreboard: occupancy x2 (R1 null), prefetch
// placement (R7 null / R4 spill), S-batching (R7 null), L2 BW (R9: half
// traffic -> slower), ring stagger (R10 null). Only setprio moved it (R2
// -12%). Remaining headroom needs the m214-class in-register-softmax
// restructure -- deferred while cheaper wins remain in the GEMMs.
// R4/R8 LESSONS: no K double-buffer regs, no tight launch_bounds (spill).
// ---------------------------------------------------------------------------
#define NQ_   2                 // 16-row q sub-tiles per block
#define QB_   (NQ_ * 16)        // 32 queries per block
#define NQT_  (N_ / QB_)        // 64 q-tiles per bh

__global__ __launch_bounds__(128, 3)
void flash_mfma_kernel(const u16* __restrict__ qkv,
                       const u16* __restrict__ kpack,
                       const u16* __restrict__ vpack,
                       u16* __restrict__ attnb) {
    __shared__ __attribute__((aligned(16))) u16 Ps[2][QB_ * 64];  // per-wave P
    __shared__ __attribute__((aligned(16))) float Oex[QB_ * 64];  // exchange
    __shared__ float lex[QB_];

    const int tid = threadIdx.x;
    const int w = tid >> 6, l = tid & 63;
    const int lq = l & 15, quad = l >> 4;
    const int sw = lq & 7;                 // P-row swizzle key

    // XCD-pinned remap: xcd = lin&7 owns bh {3x..3x+2}; NQT_ q-tiles per bh.
    const int lin  = blockIdx.x;
    const int slot = lin >> 3;                        // 0..191
    const int bh   = (lin & 7) * 3 + (slot / NQT_);   // 0..23
    const int qt   = slot & (NQT_ - 1);               // 32-query tile
    const int b = bh / H_, h = bh % H_;
    const size_t qbase = (size_t)b * N_ * QKVC + h * HD_;
    const size_t tbase = (size_t)bh * 32 * 4096;    // packed-tile base for bh

    // Q B-frags (both waves: same QB_ queries)
    bf16x8 qb[NQ_][2];
#pragma unroll
    for (int nq = 0; nq < NQ_; ++nq)
#pragma unroll
        for (int ks = 0; ks < 2; ++ks)
            qb[nq][ks] = *(const bf16x8*)
                &qkv[qbase + (size_t)(qt * QB_ + nq * 16 + lq) * QKVC
                     + ks * 32 + quad * 8];

    float lsum[NQ_];
#pragma unroll
    for (int nq = 0; nq < NQ_; ++nq) lsum[nq] = 0.f;
    f32x4 oacc[4][NQ_];
    const f32x4 z4 = {0.f, 0.f, 0.f, 0.f};
#pragma unroll
    for (int mb = 0; mb < 4; ++mb)
#pragma unroll
        for (int nq = 0; nq < NQ_; ++nq) oacc[mb][nq] = z4;

    // preload K frags for first key tile (kt = w); fully coalesced 1KB loads
    bf16x8 ka[4][2];
#pragma unroll
    for (int kb = 0; kb < 4; ++kb)
#pragma unroll
        for (int ks = 0; ks < 2; ++ks)
            ka[kb][ks] = *(const bf16x8*)
                &kpack[tbase + (size_t)w * 4096 + ((kb * 2 + ks) * 64 + l) * 8];

    for (int kt2 = 0; kt2 < 16; ++kt2) {
        const int kt  = 2 * kt2 + w;
        const int ktn = (kt + 2) & 31;       // prefetch target (wrap harmless)
        const size_t vb = tbase + (size_t)kt * 4096;
        const size_t kb_n = tbase + (size_t)ktn * 4096;

        // V frags — issued early, consumed at PV below
        bf16x8 va[4][2];
#pragma unroll
        for (int mb = 0; mb < 4; ++mb)
#pragma unroll
            for (int ks = 0; ks < 2; ++ks)
                va[mb][ks] = *(const bf16x8*)
                    &vpack[vb + ((mb * 2 + ks) * 64 + l) * 8];

        // per-kb: S-MFMAs -> exp2 -> P-write (keeps sacc lifetime short)
#pragma unroll
        for (int kb = 0; kb < 4; ++kb) {
            f32x4 sacc[NQ_];
#pragma unroll
            for (int nq = 0; nq < NQ_; ++nq) sacc[nq] = z4;
            __builtin_amdgcn_s_setprio(1);
#pragma unroll
            for (int ks = 0; ks < 2; ++ks)
#pragma unroll
                for (int nq = 0; nq < NQ_; ++nq)
                    sacc[nq] = __builtin_amdgcn_mfma_f32_16x16x32_bf16(
                        ka[kb][ks], qb[nq][ks], sacc[nq], 0, 0, 0);
            __builtin_amdgcn_s_setprio(0);
#pragma unroll
            for (int nq = 0; nq < NQ_; ++nq) {
                float p[4];
#pragma unroll
                for (int r = 0; r < 4; ++r) p[r] = fexp2(sacc[nq][r] - SMAX);
                lsum[nq] += (p[0] + p[1]) + (p[2] + p[3]);
                uint2 pkv = { pk2(p[0], p[1]), pk2(p[2], p[3]) };
                *(uint2*)&Ps[w][(nq * 16 + lq) * 64
                                + (((kb * 2 + (quad >> 1)) ^ sw) * 8)
                                + (quad & 1) * 4] = pkv;
            }
        }

        // prefetch next K tile IN-PLACE (after all S-MFMAs consumed ka)
#pragma unroll
        for (int kb = 0; kb < 4; ++kb)
#pragma unroll
            for (int ks = 0; ks < 2; ++ks)
                ka[kb][ks] = *(const bf16x8*)
                    &kpack[kb_n + ((kb * 2 + ks) * 64 + l) * 8];

        // P B-frags (same-wave LDS RAW: DS-pipe ordered, no barrier)
        bf16x8 pb[2][NQ_];
#pragma unroll
        for (int ks = 0; ks < 2; ++ks)
#pragma unroll
            for (int nq = 0; nq < NQ_; ++nq)
                pb[ks][nq] = *(const bf16x8*)
                    &Ps[w][(nq * 16 + lq) * 64 + (((ks * 4 + quad) ^ sw) * 8)];

        // O^T += V^T.P^T
        __builtin_amdgcn_s_setprio(1);
#pragma unroll
        for (int mb = 0; mb < 4; ++mb)
#pragma unroll
            for (int ks = 0; ks < 2; ++ks)
#pragma unroll
                for (int nq = 0; nq < NQ_; ++nq)
                    oacc[mb][nq] = __builtin_amdgcn_mfma_f32_16x16x32_bf16(
                        va[mb][ks], pb[ks][nq], oacc[mb][nq], 0, 0, 0);
        __builtin_amdgcn_s_setprio(0);
    }

    // finish l: reduce over quad groups
#pragma unroll
    for (int nq = 0; nq < NQ_; ++nq) {
        lsum[nq] += __shfl_xor(lsum[nq], 16, 64);
        lsum[nq] += __shfl_xor(lsum[nq], 32, 64);
    }

    // combine key-halves: wave1 -> LDS, barrier, wave0 finalizes
    if (w == 1) {
#pragma unroll
        for (int nq = 0; nq < NQ_; ++nq) {
#pragma unroll
            for (int mb = 0; mb < 4; ++mb) {
                const int chunk = (mb * 4 + quad) ^ lq;   // float4-chunk swizzle
                *(float4*)&Oex[(nq * 16 + lq) * 64 + chunk * 4] =
                    *(float4*)&oacc[mb][nq];
            }
            if (quad == 0) lex[nq * 16 + lq] = lsum[nq];
        }
    }
    __syncthreads();
    if (w == 0) {
#pragma unroll
        for (int nq = 0; nq < NQ_; ++nq) {
            const int qrow = nq * 16 + lq;
            const float inv = 1.f / (lsum[nq] + lex[qrow]);
#pragma unroll
            for (int mb = 0; mb < 4; ++mb) {
                const int chunk = (mb * 4 + quad) ^ lq;
                const float4 oe = *(const float4*)&Oex[qrow * 64 + chunk * 4];
                const float o0 = (oacc[mb][nq][0] + oe.x) * inv;
                const float o1 = (oacc[mb][nq][1] + oe.y) * inv;
                const float o2 = (oacc[mb][nq][2] + oe.z) * inv;
                const float o3 = (oacc[mb][nq][3] + oe.w) * inv;
                uint2 ov = { pk2(o0, o1), pk2(o2, o3) };
                *(uint2*)&Ps[0][qrow * 64
                                + (((mb * 2 + (quad >> 1)) ^ sw) * 8)
                                + (quad & 1) * 4] = ov;
            }
        }
        // coalesced 16B stores of QB_ q x 64 dv
#pragma unroll
        for (int pass = 0; pass < QB_ / 8; ++pass) {
            const int ql = pass * 8 + (l >> 3);          // 0..QB_-1
            const int c  = l & 7;                        // dv chunk
            const bf16x8 v = *(const bf16x8*)&Ps[0][ql * 64 + ((c ^ (ql & 7)) * 8)];
            const int query = qt * QB_ + ql;
            *(bf16x8*)&attnb[(size_t)(b * N_ + query) * C_ + h * HD_ + c * 8] = v;
        }
    }
}

// ---------------------------------------------------------------------------
extern "C" void kernel_launch(void* const* d_in, const int* in_sizes, int n_in,
                              void* d_out, int out_size, void* d_ws, size_t ws_size,
                              hipStream_t stream) {
    const float* x        = (const float*)d_in[0];
    const float* rope_cos = (const float*)d_in[1];
    const float* rope_sin = (const float*)d_in[2];
    const float* qkv_w    = (const float*)d_in[3];
    const float* qkv_b    = (const float*)d_in[4];
    const float* proj_w   = (const float*)d_in[5];
    const float* proj_b   = (const float*)d_in[6];
    const float* q_nw     = (const float*)d_in[7];
    const float* k_nw     = (const float*)d_in[8];
    float* out = (float*)d_out;

    // ws layout (bf16 buffers), ~42.5 MB. kpackb ALIASES xb: xb is dead after
    // gemm1; normvpack (writes kpackb) runs after gemm1 on the same stream.
    u16* xb    = (u16*)d_ws;                               // 4096x768
    u16* qwt   = xb    + (size_t)NROWS * C_;               // 2304x768 (W^T)
    u16* pwt   = qwt   + (size_t)QKVC * C_;                // 768x768  (W^T)
    u16* qkvb  = pwt   + (size_t)C_ * C_;                  // 4096x2304
    u16* vpackb= qkvb  + (size_t)NROWS * QKVC;             // 24x32x4096
    u16* attnb = vpackb+ (size_t)B_ * H_ * 32 * 4096;      // 4096x768
    u16* kpackb= xb;                                       // 24x32x4096 (alias)

    prep_kernel<<<dim3(576 + NROWS * C_ / 1024), 256, 0, stream>>>(
        x, xb, qkv_w, qwt, proj_w, pwt);

    gemm_tn_kernel<true, 128><<<dim3(QKVC / 128, NROWS / 128), 256, 0, stream>>>(
        xb, qwt, qkv_b, qkvb, NROWS, QKVC, C_);

    normvpack_kernel<<<dim3(768 + NROWS * H_ / 16), 256, 0, stream>>>(
        qkvb, kpackb, vpackb, rope_cos, rope_sin, q_nw, k_nw);

    flash_mfma_kernel<<<dim3(B_ * H_ * NQT_), 128, 0, stream>>>(
        qkvb, kpackb, vpackb, attnb);

    gemm_tn_kernel<false, 64><<<dim3(C_ / 64, NROWS / 128), 256, 0, stream>>>(
        attnb, pwt, proj_b, out, NROWS, C_, C_);
}